// Round 1
// baseline (2948.178 us; speedup 1.0000x reference)
//
#include <hip/hip_runtime.h>
#include <hip/hip_bf16.h>

#define E 1024
#define SLEN 1024
#define QKV3 3072
#define HD 64

typedef unsigned short u16;
typedef unsigned int   u32;
typedef __bf16 bf16x8 __attribute__((ext_vector_type(8)));
typedef float  f32x4  __attribute__((ext_vector_type(4)));

__device__ __forceinline__ u16 f2bf(float f) {
  __hip_bfloat16 h = __float2bfloat16(f);
  return __builtin_bit_cast(u16, h);
}
__device__ __forceinline__ u32 pk2(float a, float b) {
  return (u32)f2bf(a) | ((u32)f2bf(b) << 16);
}
__device__ __forceinline__ uint4 pack8(const float4& x, const float4& y) {
  return make_uint4(pk2(x.x,x.y), pk2(x.z,x.w), pk2(y.x,y.y), pk2(y.z,y.w));
}

// 16B-granule swizzles (conflict-free aggregate for the frag-read patterns)
__device__ __forceinline__ int swzA(int row, int ch) { return (row<<2) + (ch ^ (row & 3)); } // [*][32]bf16
__device__ __forceinline__ int swzK(int row, int ch) { return (row<<3) + (ch ^ (row & 7)); } // [*][64]bf16
__device__ __forceinline__ int swzP(int row, int ch) { return (row<<4) + (ch ^ (row & 7)); } // [*][128]bf16

// ---------------- GEMM: C[M][N] = A[M][K] @ W[N][K]^T + bias (+GELU) ----------
// 128x128 tile, BK=32, 256 threads (4 waves, 2x2), double-buffered LDS,
// f32->bf16 conversion during staging.
template<int GELU>
__global__ __launch_bounds__(256)
void gemm_bt(const float* __restrict__ A, const float* __restrict__ W,
             const float* __restrict__ bias, float* __restrict__ C,
             int M, int N, int K)
{
  __shared__ uint4 lsA[2][512];
  __shared__ uint4 lsB[2][512];

  const int t = threadIdx.x;
  const int lane = t & 63;
  const int w = t >> 6;
  const int wr = (w >> 1) << 6;
  const int wc = (w & 1) << 6;
  const int r = lane & 15;
  const int g = lane >> 4;

  const int row0 = blockIdx.y << 7;
  const int col0 = blockIdx.x << 7;

  const int srow = t >> 1;          // 0..127
  const int sk   = (t & 1) << 4;    // element offset 0/16 within BK=32
  const int scb  = (t & 1) << 1;    // granule chunk base 0/2

  const float* Ab = A + (size_t)(row0 + srow) * K + sk;
  const float* Wb = W + (size_t)(col0 + srow) * K + sk;

  f32x4 acc[4][4];
  #pragma unroll
  for (int i=0;i<4;i++)
    #pragma unroll
    for (int j=0;j<4;j++)
      acc[i][j] = f32x4{0.f,0.f,0.f,0.f};

  const int nk = K >> 5;

  auto stage = [&](int kt, int buf) {
    const float* ap = Ab + (kt << 5);
    const float* wp = Wb + (kt << 5);
    float4 a0 = *(const float4*)(ap + 0);
    float4 a1 = *(const float4*)(ap + 4);
    float4 a2 = *(const float4*)(ap + 8);
    float4 a3 = *(const float4*)(ap + 12);
    float4 b0 = *(const float4*)(wp + 0);
    float4 b1 = *(const float4*)(wp + 4);
    float4 b2 = *(const float4*)(wp + 8);
    float4 b3 = *(const float4*)(wp + 12);
    lsA[buf][swzA(srow, scb+0)] = pack8(a0,a1);
    lsA[buf][swzA(srow, scb+1)] = pack8(a2,a3);
    lsB[buf][swzA(srow, scb+0)] = pack8(b0,b1);
    lsB[buf][swzA(srow, scb+1)] = pack8(b2,b3);
  };

  stage(0, 0);
  __syncthreads();

  for (int kt = 0; kt < nk; ++kt) {
    const int cur = kt & 1;
    if (kt + 1 < nk) stage(kt + 1, cur ^ 1);

    bf16x8 af[4], bfr[4];
    #pragma unroll
    for (int m=0;m<4;m++)
      af[m] = *(const bf16x8*)&lsA[cur][swzA(wr + (m<<4) + r, g)];
    #pragma unroll
    for (int n=0;n<4;n++)
      bfr[n] = *(const bf16x8*)&lsB[cur][swzA(wc + (n<<4) + r, g)];
    #pragma unroll
    for (int m=0;m<4;m++)
      #pragma unroll
      for (int n=0;n<4;n++)
        acc[m][n] = __builtin_amdgcn_mfma_f32_16x16x32_bf16(af[m], bfr[n], acc[m][n], 0, 0, 0);

    __syncthreads();
  }

  // epilogue: D row = 4*g + q, col = lane&15 (HW-verified mapping)
  #pragma unroll
  for (int n=0;n<4;n++) {
    const int col = col0 + wc + (n<<4) + r;
    const float bv = bias[col];
    #pragma unroll
    for (int m=0;m<4;m++) {
      const int rowb = row0 + wr + (m<<4) + (g<<2);
      #pragma unroll
      for (int q=0;q<4;q++) {
        float v = acc[m][n][q] + bv;
        if (GELU) v = 0.5f * v * (1.f + erff(v * 0.70710678118f));
        C[(size_t)(rowb + q) * N + col] = v;
      }
    }
  }
}

// ---------------- Flash attention ------------------------------------------
// grid (8 q-tiles, 32 b*head); block 256 = 4 waves, wave owns 32 queries.
// qkv: [2048][3072] f32 (q|k|v). o: [2048][1024] f32.
__global__ __launch_bounds__(256)
void attn_fwd(const float* __restrict__ qkv, float* __restrict__ o)
{
  __shared__ uint4 sK4[1024];                    // [128][64] bf16, swizzled (16KB)
  __shared__ __align__(16) u16 sV[64*136];       // V^T [64][128+8pad] bf16 (17KB)
  __shared__ __align__(16) u16 sP[4*32*128];     // per-wave P [32][128] bf16 swizzled (32KB)

  const int qt = blockIdx.x;
  const int bn = blockIdx.y;
  const int b  = bn >> 4;
  const int hd = bn & 15;

  const int t = threadIdx.x;
  const int lane = t & 63;
  const int w = t >> 6;
  const int r = lane & 15;
  const int g = lane >> 4;

  // Q fragments in registers, scaled by (1/sqrt(64)) * log2(e) for exp2 softmax
  const float SC = 0.125f * 1.44269504089f;
  bf16x8 qf[2][2];
  #pragma unroll
  for (int m=0;m<2;m++)
    #pragma unroll
    for (int kk=0;kk<2;kk++) {
      const float* qp = qkv + (size_t)(b*SLEN + qt*128 + w*32 + (m<<4) + r) * QKV3
                      + hd*HD + (kk<<5) + (g<<3);
      float4 q0 = *(const float4*)(qp);
      float4 q1 = *(const float4*)(qp+4);
      q0.x*=SC; q0.y*=SC; q0.z*=SC; q0.w*=SC;
      q1.x*=SC; q1.y*=SC; q1.z*=SC; q1.w*=SC;
      qf[m][kk] = __builtin_bit_cast(bf16x8, pack8(q0,q1));
    }

  float m_run[2][4], l_run[2][4];
  f32x4 aco[2][4];
  #pragma unroll
  for (int m=0;m<2;m++) {
    #pragma unroll
    for (int q=0;q<4;q++) { m_run[m][q] = -1e30f; l_run[m][q] = 0.f; }
    #pragma unroll
    for (int n=0;n<4;n++) aco[m][n] = f32x4{0.f,0.f,0.f,0.f};
  }

  u16* sPw = sP + (w << 12);

  const int nkt = qt + 1;
  for (int kt = 0; kt < nkt; ++kt) {
    __syncthreads();
    { // stage K tile [128 keys][64 h]
      const int krow = t >> 1;
      const int kh = (t & 1) << 5;
      const float* kp = qkv + (size_t)(b*SLEN + kt*128 + krow) * QKV3 + E + hd*HD + kh;
      float4 k0 = *(const float4*)(kp+0);
      float4 k1 = *(const float4*)(kp+4);
      float4 k2 = *(const float4*)(kp+8);
      float4 k3 = *(const float4*)(kp+12);
      float4 k4 = *(const float4*)(kp+16);
      float4 k5 = *(const float4*)(kp+20);
      float4 k6 = *(const float4*)(kp+24);
      float4 k7 = *(const float4*)(kp+28);
      const int cb = (t & 1) << 2;
      sK4[swzK(krow, cb+0)] = pack8(k0,k1);
      sK4[swzK(krow, cb+1)] = pack8(k2,k3);
      sK4[swzK(krow, cb+2)] = pack8(k4,k5);
      sK4[swzK(krow, cb+3)] = pack8(k6,k7);
    }
    { // stage V transposed [64 h][128 keys]
      const int vh = t & 63;
      const int tb = (t >> 6) << 5;
      const float* vp = qkv + (size_t)(b*SLEN + kt*128 + tb) * QKV3 + 2*E + hd*HD + vh;
      #pragma unroll
      for (int i=0;i<32;i+=2) {
        float v0 = vp[(size_t)i * QKV3];
        float v1 = vp[(size_t)(i+1) * QKV3];
        const int tt = tb + i;
        const int gran = vh*17 + (tt >> 3);
        *(u32*)&sV[(gran<<3) + (tt & 7)] = pk2(v0, v1);
      }
    }
    __syncthreads();

    // QK^T
    f32x4 s[2][8];
    #pragma unroll
    for (int m=0;m<2;m++)
      #pragma unroll
      for (int n=0;n<8;n++)
        s[m][n] = f32x4{0.f,0.f,0.f,0.f};
    #pragma unroll
    for (int kk=0;kk<2;kk++) {
      bf16x8 kf[8];
      #pragma unroll
      for (int n=0;n<8;n++)
        kf[n] = *(const bf16x8*)&sK4[swzK((n<<4)+r, (kk<<2)+g)];
      #pragma unroll
      for (int m=0;m<2;m++)
        #pragma unroll
        for (int n=0;n<8;n++)
          s[m][n] = __builtin_amdgcn_mfma_f32_16x16x32_bf16(qf[m][kk], kf[n], s[m][n], 0,0,0);
    }

    if (kt == qt) { // causal mask on diagonal tile (key-pad mask is vacuous: x>=1)
      #pragma unroll
      for (int m=0;m<2;m++)
        #pragma unroll
        for (int n=0;n<8;n++) {
          const int tg = (n<<4) + r;
          #pragma unroll
          for (int q=0;q<4;q++) {
            const int qg = w*32 + (m<<4) + (g<<2) + q;
            if (tg > qg) s[m][n][q] = -1e30f;
          }
        }
    }

    // online softmax (exp2 domain) + P -> LDS (bf16)
    #pragma unroll
    for (int m=0;m<2;m++) {
      float f[4], rs[4];
      #pragma unroll
      for (int q=0;q<4;q++) {
        float v = s[m][0][q];
        #pragma unroll
        for (int n=1;n<8;n++) v = fmaxf(v, s[m][n][q]);
        v = fmaxf(v, __shfl_xor(v, 1));
        v = fmaxf(v, __shfl_xor(v, 2));
        v = fmaxf(v, __shfl_xor(v, 4));
        v = fmaxf(v, __shfl_xor(v, 8));
        const float mn = fmaxf(m_run[m][q], v);
        f[q] = exp2f(m_run[m][q] - mn);
        m_run[m][q] = mn;
        rs[q] = 0.f;
      }
      #pragma unroll
      for (int n=0;n<8;n++) {
        #pragma unroll
        for (int q=0;q<4;q++) {
          const float p = exp2f(s[m][n][q] - m_run[m][q]);
          rs[q] += p;
          const int prow = (m<<4) + (g<<2) + q;
          const int pch = (n<<1) + (r>>3);
          sPw[(swzP(prow, pch)<<3) + (r&7)] = f2bf(p);
        }
      }
      #pragma unroll
      for (int q=0;q<4;q++) {
        rs[q] += __shfl_xor(rs[q], 1);
        rs[q] += __shfl_xor(rs[q], 2);
        rs[q] += __shfl_xor(rs[q], 4);
        rs[q] += __shfl_xor(rs[q], 8);
        l_run[m][q] = l_run[m][q]*f[q] + rs[q];
      }
      #pragma unroll
      for (int n=0;n<4;n++)
        #pragma unroll
        for (int q=0;q<4;q++)
          aco[m][n][q] *= f[q];
    }

    __builtin_amdgcn_s_waitcnt(0); // P writes visible to own-wave cross-lane reads

    // PV: A = P [32 q][128 t], B = V^T
    #pragma unroll
    for (int kk=0;kk<4;kk++) {
      bf16x8 pf[2], vf[4];
      #pragma unroll
      for (int m=0;m<2;m++)
        pf[m] = *(const bf16x8*)&sPw[swzP((m<<4)+r, (kk<<2)+g)<<3];
      #pragma unroll
      for (int n=0;n<4;n++)
        vf[n] = *(const bf16x8*)&sV[(((n<<4)+r)*17 + (kk<<2) + g)<<3];
      #pragma unroll
      for (int m=0;m<2;m++)
        #pragma unroll
        for (int n=0;n<4;n++)
          aco[m][n] = __builtin_amdgcn_mfma_f32_16x16x32_bf16(pf[m], vf[n], aco[m][n], 0,0,0);
    }
  }

  #pragma unroll
  for (int m=0;m<2;m++)
    #pragma unroll
    for (int n=0;n<4;n++) {
      const int col = hd*HD + (n<<4) + r;
      #pragma unroll
      for (int q=0;q<4;q++) {
        const int qg = qt*128 + w*32 + (m<<4) + (g<<2) + q;
        o[(size_t)(b*SLEN + qg) * E + col] = aco[m][n][q] / l_run[m][q];
      }
    }
}

// ---------------- LayerNorm (+ optional residual), one block per row --------
__global__ __launch_bounds__(256)
void ln_row(const float* __restrict__ a, const float* __restrict__ res,
            const float* __restrict__ lw, const float* __restrict__ lb,
            float* __restrict__ out)
{
  __shared__ float red[8];
  const int row = blockIdx.x;
  const int i = threadIdx.x;
  const float4* ap = (const float4*)(a + ((size_t)row << 10));
  float4 v = ap[i];
  if (res != nullptr) {
    const float4 rv = ((const float4*)(res + ((size_t)row << 10)))[i];
    v.x += rv.x; v.y += rv.y; v.z += rv.z; v.w += rv.w;
  }
  float s1 = v.x + v.y + v.z + v.w;
  float s2 = v.x*v.x + v.y*v.y + v.z*v.z + v.w*v.w;
  #pragma unroll
  for (int off=1; off<64; off<<=1) { s1 += __shfl_xor(s1, off); s2 += __shfl_xor(s2, off); }
  if ((i & 63) == 0) { red[(i>>6)*2] = s1; red[(i>>6)*2+1] = s2; }
  __syncthreads();
  s1 = red[0] + red[2] + red[4] + red[6];
  s2 = red[1] + red[3] + red[5] + red[7];
  const float mean = s1 * (1.f/1024.f);
  const float var  = s2 * (1.f/1024.f) - mean*mean;
  const float rstd = rsqrtf(var + 1e-5f);
  const float4 wv = ((const float4*)lw)[i];
  const float4 bv = ((const float4*)lb)[i];
  float4 ov;
  ov.x = (v.x - mean)*rstd*wv.x + bv.x;
  ov.y = (v.y - mean)*rstd*wv.y + bv.y;
  ov.z = (v.z - mean)*rstd*wv.z + bv.z;
  ov.w = (v.w - mean)*rstd*wv.w + bv.w;
  ((float4*)(out + ((size_t)row << 10)))[i] = ov;
}

// ---------------- Embedding + decoder LN ------------------------------------
__global__ __launch_bounds__(256)
void embed_ln(const int* __restrict__ x, const float* __restrict__ tok,
              const float* __restrict__ pos, const float* __restrict__ lw,
              const float* __restrict__ lb, float* __restrict__ h)
{
  __shared__ float red[8];
  const int row = blockIdx.x;            // b*S + s
  const int s = row & (SLEN-1);
  const int i = threadIdx.x;
  const int id = x[row];
  const float4 tv = ((const float4*)(tok + ((size_t)id << 10)))[i];
  const float4 pv = ((const float4*)(pos + ((size_t)s << 10)))[i];
  float4 v;
  v.x = tv.x + pv.x; v.y = tv.y + pv.y; v.z = tv.z + pv.z; v.w = tv.w + pv.w;
  float s1 = v.x + v.y + v.z + v.w;
  float s2 = v.x*v.x + v.y*v.y + v.z*v.z + v.w*v.w;
  #pragma unroll
  for (int off=1; off<64; off<<=1) { s1 += __shfl_xor(s1, off); s2 += __shfl_xor(s2, off); }
  if ((i & 63) == 0) { red[(i>>6)*2] = s1; red[(i>>6)*2+1] = s2; }
  __syncthreads();
  s1 = red[0] + red[2] + red[4] + red[6];
  s2 = red[1] + red[3] + red[5] + red[7];
  const float mean = s1 * (1.f/1024.f);
  const float var  = s2 * (1.f/1024.f) - mean*mean;
  const float rstd = rsqrtf(var + 1e-5f);
  const float4 wv = ((const float4*)lw)[i];
  const float4 bv = ((const float4*)lb)[i];
  float4 ov;
  ov.x = (v.x - mean)*rstd*wv.x + bv.x;
  ov.y = (v.y - mean)*rstd*wv.y + bv.y;
  ov.z = (v.z - mean)*rstd*wv.z + bv.z;
  ov.w = (v.w - mean)*rstd*wv.w + bv.w;
  ((float4*)(h + ((size_t)row << 10)))[i] = ov;
}

extern "C" void kernel_launch(void* const* d_in, const int* in_sizes, int n_in,
                              void* d_out, int out_size, void* d_ws, size_t ws_size,
                              hipStream_t stream) {
  const int*   x    = (const int*)  d_in[0];
  const float* tok  = (const float*)d_in[1];
  const float* pos  = (const float*)d_in[2];
  const float* decw = (const float*)d_in[3];
  const float* decb = (const float*)d_in[4];
  const float* qkvw = (const float*)d_in[5];
  const float* qkvb = (const float*)d_in[6];
  const float* apw  = (const float*)d_in[7];
  const float* apb  = (const float*)d_in[8];
  const float* l1w  = (const float*)d_in[9];
  const float* l1b  = (const float*)d_in[10];
  const float* fcw  = (const float*)d_in[11];
  const float* fcb  = (const float*)d_in[12];
  const float* mpw  = (const float*)d_in[13];
  const float* mpb  = (const float*)d_in[14];
  const float* l2w  = (const float*)d_in[15];
  const float* l2b  = (const float*)d_in[16];
  const float* finw = (const float*)d_in[17];
  const float* finb = (const float*)d_in[18];
  float* out = (float*)d_out;

  // workspace layout (f32): 80 MB total
  float* h    = (float*)d_ws;                  // [2048][1024]
  float* qkv  = h    + (size_t)2048*1024;      // [2048][3072]
  float* abuf = qkv  + (size_t)2048*3072;      // [2048][1024] attn out
  float* pbuf = abuf + (size_t)2048*1024;      // [2048][1024] proj/mlp out
  float* fbuf = pbuf + (size_t)2048*1024;      // [2048][4096] fc-gelu out

  embed_ln<<<2048, 256, 0, stream>>>(x, tok, pos, decw, decb, h);

  for (int l = 0; l < 8; ++l) {
    const size_t lo1 = (size_t)l * 3072 * 1024;
    const size_t lo2 = (size_t)l * 1024 * 1024;
    const size_t lo3 = (size_t)l * 4096 * 1024;
    gemm_bt<0><<<dim3(24, 16), 256, 0, stream>>>(h, qkvw + lo1, qkvb + (size_t)l*3072, qkv, 2048, 3072, 1024);
    attn_fwd<<<dim3(8, 32), 256, 0, stream>>>(qkv, abuf);
    gemm_bt<0><<<dim3(8, 16), 256, 0, stream>>>(abuf, apw + lo2, apb + (size_t)l*1024, pbuf, 2048, 1024, 1024);
    ln_row<<<2048, 256, 0, stream>>>(pbuf, h, l1w + (size_t)l*1024, l1b + (size_t)l*1024, h);
    gemm_bt<1><<<dim3(32, 16), 256, 0, stream>>>(h, fcw + lo3, fcb + (size_t)l*4096, fbuf, 2048, 4096, 1024);
    gemm_bt<0><<<dim3(8, 16), 256, 0, stream>>>(fbuf, mpw + lo3, mpb + (size_t)l*1024, pbuf, 2048, 1024, 4096);
    ln_row<<<2048, 256, 0, stream>>>(pbuf, h, l2w + (size_t)l*1024, l2b + (size_t)l*1024, h);
  }

  ln_row<<<2048, 256, 0, stream>>>(h, nullptr, finw, finb, out);
}

// Round 2
// 1869.694 us; speedup vs baseline: 1.5768x; 1.5768x over previous
//
#include <hip/hip_runtime.h>
#include <hip/hip_bf16.h>

#define E 1024
#define SLEN 1024
#define QKV3 3072
#define HD 64

typedef unsigned short u16;
typedef unsigned int   u32;
typedef __bf16 bf16x8 __attribute__((ext_vector_type(8)));
typedef float  f32x4  __attribute__((ext_vector_type(4)));

__device__ __forceinline__ u16 f2bf(float f) {
  __hip_bfloat16 h = __float2bfloat16(f);
  return __builtin_bit_cast(u16, h);
}
__device__ __forceinline__ u32 pk2(float a, float b) {
  return (u32)f2bf(a) | ((u32)f2bf(b) << 16);
}
__device__ __forceinline__ uint4 pack8(const float4& x, const float4& y) {
  return make_uint4(pk2(x.x,x.y), pk2(x.z,x.w), pk2(y.x,y.y), pk2(y.z,y.w));
}

// async global->LDS, 16B per lane; LDS dest = wave-uniform base + lane*16
__device__ __forceinline__ void gload16(const u16* g, u16* l) {
  __builtin_amdgcn_global_load_lds(
      (const __attribute__((address_space(1))) void*)g,
      (__attribute__((address_space(3))) void*)l, 16, 0, 0);
}

// P-buffer granule swizzle (reg-staged, from round 1 — verified)
__device__ __forceinline__ int swzP(int row, int ch) { return (row<<4) + (ch ^ (row & 7)); }

// ---------------- f32 -> bf16 convert (weights pre-pass) --------------------
__global__ __launch_bounds__(256)
void f2b_conv(const float* __restrict__ src, u16* __restrict__ dst, int n8)
{
  const int i = blockIdx.x * 256 + threadIdx.x;
  if (i < n8) {
    const float4 a = ((const float4*)src)[i*2];
    const float4 b = ((const float4*)src)[i*2+1];
    ((uint4*)dst)[i] = pack8(a, b);
  }
}

// ---------------- GEMM (m97 structure): C = A[M][K] @ W[N][K]^T + bias -------
// bf16 A,W via global_load_lds; BM=128, BK=32, 256 threads (2x2 waves),
// double-buffered linear LDS; f32 or bf16 output, optional exact GELU.
template<int BN, int OUTBF, int GELU>
__global__ __launch_bounds__(256)
void gemm_lds(const u16* __restrict__ A, const u16* __restrict__ W,
              const float* __restrict__ bias, void* __restrict__ Cv,
              int M, int N, int K)
{
  constexpr int BM = 128;
  constexpr int BK = 32;
  __shared__ __align__(16) u16 sA[2][BM*BK];
  __shared__ __align__(16) u16 sB[2][BN*BK];

  const int t = threadIdx.x;
  const int lane = t & 63;
  const int w = t >> 6;
  const int r = lane & 15;
  const int g = lane >> 4;
  const int wr = (w >> 1) * 64;
  const int wc = (w & 1) * (BN/2);

  const int row0 = blockIdx.y * BM;
  const int col0 = blockIdx.x * BN;

  constexpr int ACH = BM/16;            // 1024B chunks in A tile
  constexpr int NCH = ACH + BN/16;      // total chunks
  constexpr int CPW = NCH/4;            // chunks per wave

  const int lrow = lane >> 2;           // row within 16-row chunk
  const int lcol = (lane & 3) << 3;     // bf16 col offset (8-elem granule)

  f32x4 acc[4][BN/32];
  #pragma unroll
  for (int i=0;i<4;i++)
    #pragma unroll
    for (int j=0;j<BN/32;j++)
      acc[i][j] = f32x4{0.f,0.f,0.f,0.f};

  const int nk = K >> 5;

  auto stage = [&](int kt, int buf) {
    #pragma unroll
    for (int i = 0; i < CPW; ++i) {
      const int c = w*CPW + i;
      if (c < ACH) {
        const u16* gp = A + (size_t)(row0 + c*16 + lrow) * K + (kt<<5) + lcol;
        gload16(gp, &sA[buf][c*512]);
      } else {
        const int cb = c - ACH;
        const u16* gp = W + (size_t)(col0 + cb*16 + lrow) * K + (kt<<5) + lcol;
        gload16(gp, &sB[buf][cb*512]);
      }
    }
  };

  stage(0, 0);

  for (int kt = 0; kt < nk; ++kt) {
    const int cur = kt & 1;
    __syncthreads();                       // drains vmcnt: buf[cur] ready
    if (kt + 1 < nk) stage(kt + 1, cur ^ 1);

    bf16x8 af[4], bfr[BN/32];
    #pragma unroll
    for (int m=0;m<4;m++)
      af[m] = *(const bf16x8*)&sA[cur][(wr + (m<<4) + r)*32 + (g<<3)];
    #pragma unroll
    for (int n=0;n<BN/32;n++)
      bfr[n] = *(const bf16x8*)&sB[cur][(wc + (n<<4) + r)*32 + (g<<3)];
    #pragma unroll
    for (int m=0;m<4;m++)
      #pragma unroll
      for (int n=0;n<BN/32;n++)
        acc[m][n] = __builtin_amdgcn_mfma_f32_16x16x32_bf16(af[m], bfr[n], acc[m][n], 0, 0, 0);
  }

  #pragma unroll
  for (int n=0;n<BN/32;n++) {
    const int col = col0 + wc + (n<<4) + r;
    const float bv = bias[col];
    #pragma unroll
    for (int m=0;m<4;m++) {
      const int rowb = row0 + wr + (m<<4) + (g<<2);
      #pragma unroll
      for (int q=0;q<4;q++) {
        float v = acc[m][n][q] + bv;
        if (GELU) v = 0.5f * v * (1.f + erff(v * 0.70710678118f));
        if (OUTBF) ((u16*)Cv)[(size_t)(rowb + q) * N + col] = f2bf(v);
        else       ((float*)Cv)[(size_t)(rowb + q) * N + col] = v;
      }
    }
  }
}

// ---------------- Flash attention (bf16 qkv in, bf16 out) -------------------
// grid (8 q-tiles, 32 b*head); 4 waves, wave owns 32 queries.
__global__ __launch_bounds__(256)
void attn_fwd(const u16* __restrict__ qkv, u16* __restrict__ o)
{
  __shared__ __align__(16) u16 sK[128*64];   // [128 keys][64 h], XOR-swizzled granules (16KB)
  __shared__ __align__(16) u16 sV[64*136];   // V^T [64 h][128+8 t] granule layout (17KB)
  __shared__ __align__(16) u16 sP[4*32*128]; // per-wave P [32][128] swizzled (32KB)

  const int qt = blockIdx.x;
  const int bn = blockIdx.y;
  const int b  = bn >> 4;
  const int hd = bn & 15;

  const int t = threadIdx.x;
  const int lane = t & 63;
  const int w = t >> 6;
  const int r = lane & 15;
  const int g = lane >> 4;

  // softmax scale folded post-MFMA (exp2 domain)
  const float SC = 0.125f * 1.44269504089f;

  // Q fragments straight from bf16
  bf16x8 qf[2][2];
  #pragma unroll
  for (int m=0;m<2;m++)
    #pragma unroll
    for (int kk=0;kk<2;kk++)
      qf[m][kk] = *(const bf16x8*)(qkv + (size_t)(b*SLEN + qt*128 + w*32 + (m<<4) + r) * QKV3
                                   + hd*HD + (kk<<5) + (g<<3));

  float m_run[2][4], l_run[2][4];
  f32x4 aco[2][4];
  #pragma unroll
  for (int m=0;m<2;m++) {
    #pragma unroll
    for (int q=0;q<4;q++) { m_run[m][q] = -1e30f; l_run[m][q] = 0.f; }
    #pragma unroll
    for (int n=0;n<4;n++) aco[m][n] = f32x4{0.f,0.f,0.f,0.f};
  }

  u16* sPw = sP + (w << 12);

  const int nkt = qt + 1;
  for (int kt = 0; kt < nkt; ++kt) {
    __syncthreads();  // prior tile's PV reads done before restaging
    { // K tile via global_load_lds, pre-swizzled source (row&7 XOR on 16B granule)
      const int rl = lane >> 3;                  // row within 8-row chunk
      const int hc = (lane & 7) ^ rl;            // fetched h-granule
      #pragma unroll
      for (int i=0;i<4;i++) {
        const int c = w*4 + i;
        const u16* gp = qkv + (size_t)(b*SLEN + kt*128 + c*8 + rl) * QKV3
                      + E + hd*HD + (hc<<3);
        gload16(gp, &sK[c*512]);
      }
    }
    { // V^T reg-staged
      const int vh = t & 63;
      const int tb = (t >> 6) << 5;
      const u16* vp = qkv + (size_t)(b*SLEN + kt*128 + tb) * QKV3 + 2*E + hd*HD + vh;
      #pragma unroll
      for (int i=0;i<32;i+=2) {
        const u32 v0 = vp[(size_t)i * QKV3];
        const u32 v1 = vp[(size_t)(i+1) * QKV3];
        const int tt = tb + i;
        const int gran = vh*17 + (tt >> 3);
        *(u32*)&sV[(gran<<3) + (tt & 7)] = v0 | (v1 << 16);
      }
    }
    __syncthreads();

    // QK^T
    f32x4 s[2][8];
    #pragma unroll
    for (int m=0;m<2;m++)
      #pragma unroll
      for (int n=0;n<8;n++)
        s[m][n] = f32x4{0.f,0.f,0.f,0.f};
    #pragma unroll
    for (int kk=0;kk<2;kk++) {
      bf16x8 kf[8];
      #pragma unroll
      for (int n=0;n<8;n++)
        kf[n] = *(const bf16x8*)&sK[((n<<4)+r)*64 + ((((kk<<2)+g) ^ (r&7))<<3)];
      #pragma unroll
      for (int m=0;m<2;m++)
        #pragma unroll
        for (int n=0;n<8;n++)
          s[m][n] = __builtin_amdgcn_mfma_f32_16x16x32_bf16(qf[m][kk], kf[n], s[m][n], 0,0,0);
    }
    #pragma unroll
    for (int m=0;m<2;m++)
      #pragma unroll
      for (int n=0;n<8;n++)
        #pragma unroll
        for (int q=0;q<4;q++)
          s[m][n][q] *= SC;

    if (kt == qt) { // causal mask (key-pad vacuous: token ids >= 1)
      #pragma unroll
      for (int m=0;m<2;m++)
        #pragma unroll
        for (int n=0;n<8;n++) {
          const int tg = (n<<4) + r;
          #pragma unroll
          for (int q=0;q<4;q++) {
            const int qg = w*32 + (m<<4) + (g<<2) + q;
            if (tg > qg) s[m][n][q] = -1e30f;
          }
        }
    }

    // online softmax (exp2 domain) + P -> LDS (bf16)
    #pragma unroll
    for (int m=0;m<2;m++) {
      float f[4], rs[4];
      #pragma unroll
      for (int q=0;q<4;q++) {
        float v = s[m][0][q];
        #pragma unroll
        for (int n=1;n<8;n++) v = fmaxf(v, s[m][n][q]);
        v = fmaxf(v, __shfl_xor(v, 1));
        v = fmaxf(v, __shfl_xor(v, 2));
        v = fmaxf(v, __shfl_xor(v, 4));
        v = fmaxf(v, __shfl_xor(v, 8));
        const float mn = fmaxf(m_run[m][q], v);
        f[q] = exp2f(m_run[m][q] - mn);
        m_run[m][q] = mn;
        rs[q] = 0.f;
      }
      #pragma unroll
      for (int n=0;n<8;n++) {
        #pragma unroll
        for (int q=0;q<4;q++) {
          const float p = exp2f(s[m][n][q] - m_run[m][q]);
          rs[q] += p;
          const int prow = (m<<4) + (g<<2) + q;
          const int pch = (n<<1) + (r>>3);
          sPw[(swzP(prow, pch)<<3) + (r&7)] = f2bf(p);
        }
      }
      #pragma unroll
      for (int q=0;q<4;q++) {
        rs[q] += __shfl_xor(rs[q], 1);
        rs[q] += __shfl_xor(rs[q], 2);
        rs[q] += __shfl_xor(rs[q], 4);
        rs[q] += __shfl_xor(rs[q], 8);
        l_run[m][q] = l_run[m][q]*f[q] + rs[q];
      }
      #pragma unroll
      for (int n=0;n<4;n++)
        #pragma unroll
        for (int q=0;q<4;q++)
          aco[m][n][q] *= f[q];
    }

    __builtin_amdgcn_s_waitcnt(0);        // own-wave P writes visible
    __builtin_amdgcn_sched_barrier(0);    // rule #18: pin MFMA after the wait

    // PV
    #pragma unroll
    for (int kk=0;kk<4;kk++) {
      bf16x8 pf[2], vf[4];
      #pragma unroll
      for (int m=0;m<2;m++)
        pf[m] = *(const bf16x8*)&sPw[swzP((m<<4)+r, (kk<<2)+g)<<3];
      #pragma unroll
      for (int n=0;n<4;n++)
        vf[n] = *(const bf16x8*)&sV[(((n<<4)+r)*17 + (kk<<2) + g)<<3];
      #pragma unroll
      for (int m=0;m<2;m++)
        #pragma unroll
        for (int n=0;n<4;n++)
          aco[m][n] = __builtin_amdgcn_mfma_f32_16x16x32_bf16(pf[m], vf[n], aco[m][n], 0,0,0);
    }
  }

  #pragma unroll
  for (int m=0;m<2;m++)
    #pragma unroll
    for (int n=0;n<4;n++) {
      const int col = hd*HD + (n<<4) + r;
      #pragma unroll
      for (int q=0;q<4;q++) {
        const int qg = qt*128 + w*32 + (m<<4) + (g<<2) + q;
        o[(size_t)(b*SLEN + qg) * E + col] = f2bf(aco[m][n][q] / l_run[m][q]);
      }
    }
}

// ---------------- LayerNorm (+res), dual f32/bf16 outputs -------------------
__global__ __launch_bounds__(256)
void ln_row(const float* __restrict__ a, const float* __restrict__ res,
            const float* __restrict__ lw, const float* __restrict__ lb,
            float* __restrict__ out32, u16* __restrict__ outb)
{
  __shared__ float red[8];
  const int row = blockIdx.x;
  const int i = threadIdx.x;
  float4 v = ((const float4*)(a + ((size_t)row << 10)))[i];
  if (res != nullptr) {
    const float4 rv = ((const float4*)(res + ((size_t)row << 10)))[i];
    v.x += rv.x; v.y += rv.y; v.z += rv.z; v.w += rv.w;
  }
  float s1 = v.x + v.y + v.z + v.w;
  float s2 = v.x*v.x + v.y*v.y + v.z*v.z + v.w*v.w;
  #pragma unroll
  for (int off=1; off<64; off<<=1) { s1 += __shfl_xor(s1, off); s2 += __shfl_xor(s2, off); }
  if ((i & 63) == 0) { red[(i>>6)*2] = s1; red[(i>>6)*2+1] = s2; }
  __syncthreads();
  s1 = red[0] + red[2] + red[4] + red[6];
  s2 = red[1] + red[3] + red[5] + red[7];
  const float mean = s1 * (1.f/1024.f);
  const float var  = s2 * (1.f/1024.f) - mean*mean;
  const float rstd = rsqrtf(var + 1e-5f);
  const float4 wv = ((const float4*)lw)[i];
  const float4 bv = ((const float4*)lb)[i];
  float4 ov;
  ov.x = (v.x - mean)*rstd*wv.x + bv.x;
  ov.y = (v.y - mean)*rstd*wv.y + bv.y;
  ov.z = (v.z - mean)*rstd*wv.z + bv.z;
  ov.w = (v.w - mean)*rstd*wv.w + bv.w;
  if (out32) ((float4*)(out32 + ((size_t)row << 10)))[i] = ov;
  if (outb) {
    uint2 p; p.x = pk2(ov.x, ov.y); p.y = pk2(ov.z, ov.w);
    ((uint2*)(outb + ((size_t)row << 10)))[i] = p;
  }
}

// ---------------- Embedding + decoder LN, dual outputs ----------------------
__global__ __launch_bounds__(256)
void embed_ln(const int* __restrict__ x, const float* __restrict__ tok,
              const float* __restrict__ pos, const float* __restrict__ lw,
              const float* __restrict__ lb, float* __restrict__ h32,
              u16* __restrict__ hb)
{
  __shared__ float red[8];
  const int row = blockIdx.x;
  const int s = row & (SLEN-1);
  const int i = threadIdx.x;
  const int id = x[row];
  const float4 tv = ((const float4*)(tok + ((size_t)id << 10)))[i];
  const float4 pv = ((const float4*)(pos + ((size_t)s << 10)))[i];
  float4 v;
  v.x = tv.x + pv.x; v.y = tv.y + pv.y; v.z = tv.z + pv.z; v.w = tv.w + pv.w;
  float s1 = v.x + v.y + v.z + v.w;
  float s2 = v.x*v.x + v.y*v.y + v.z*v.z + v.w*v.w;
  #pragma unroll
  for (int off=1; off<64; off<<=1) { s1 += __shfl_xor(s1, off); s2 += __shfl_xor(s2, off); }
  if ((i & 63) == 0) { red[(i>>6)*2] = s1; red[(i>>6)*2+1] = s2; }
  __syncthreads();
  s1 = red[0] + red[2] + red[4] + red[6];
  s2 = red[1] + red[3] + red[5] + red[7];
  const float mean = s1 * (1.f/1024.f);
  const float var  = s2 * (1.f/1024.f) - mean*mean;
  const float rstd = rsqrtf(var + 1e-5f);
  const float4 wv = ((const float4*)lw)[i];
  const float4 bv = ((const float4*)lb)[i];
  float4 ov;
  ov.x = (v.x - mean)*rstd*wv.x + bv.x;
  ov.y = (v.y - mean)*rstd*wv.y + bv.y;
  ov.z = (v.z - mean)*rstd*wv.z + bv.z;
  ov.w = (v.w - mean)*rstd*wv.w + bv.w;
  ((float4*)(h32 + ((size_t)row << 10)))[i] = ov;
  uint2 p; p.x = pk2(ov.x, ov.y); p.y = pk2(ov.z, ov.w);
  ((uint2*)(hb + ((size_t)row << 10)))[i] = p;
}

extern "C" void kernel_launch(void* const* d_in, const int* in_sizes, int n_in,
                              void* d_out, int out_size, void* d_ws, size_t ws_size,
                              hipStream_t stream) {
  const int*   x    = (const int*)  d_in[0];
  const float* tok  = (const float*)d_in[1];
  const float* pos  = (const float*)d_in[2];
  const float* decw = (const float*)d_in[3];
  const float* decb = (const float*)d_in[4];
  const float* qkvw = (const float*)d_in[5];
  const float* qkvb = (const float*)d_in[6];
  const float* apw  = (const float*)d_in[7];
  const float* apb  = (const float*)d_in[8];
  const float* l1w  = (const float*)d_in[9];
  const float* l1b  = (const float*)d_in[10];
  const float* fcw  = (const float*)d_in[11];
  const float* fcb  = (const float*)d_in[12];
  const float* mpw  = (const float*)d_in[13];
  const float* mpb  = (const float*)d_in[14];
  const float* l2w  = (const float*)d_in[15];
  const float* l2b  = (const float*)d_in[16];
  const float* finw = (const float*)d_in[17];
  const float* finb = (const float*)d_in[18];
  float* out = (float*)d_out;

  // workspace (f32 + bf16 regions), ~76 MB
  char* p = (char*)d_ws;
  float* h32  = (float*)p;                 p += (size_t)2048*1024*4;   // 8 MB
  float* p32  = (float*)p;                 p += (size_t)2048*1024*4;   // 8 MB
  u16*   hb   = (u16*)p;                   p += (size_t)2048*1024*2;   // 4 MB
  u16*   qkvB = (u16*)p;                   p += (size_t)2048*3072*2;   // 12 MB
  u16*   ab   = (u16*)p;                   p += (size_t)2048*1024*2;   // 4 MB
  u16*   fb   = (u16*)p;                   p += (size_t)2048*4096*2;   // 16 MB
  u16*   wq   = (u16*)p;                   p += (size_t)3072*1024*2;   // 6 MB
  u16*   wap  = (u16*)p;                   p += (size_t)1024*1024*2;   // 2 MB
  u16*   wfc  = (u16*)p;                   p += (size_t)4096*1024*2;   // 8 MB
  u16*   wmp  = (u16*)p;                   p += (size_t)4096*1024*2;   // 8 MB

  embed_ln<<<2048, 256, 0, stream>>>(x, tok, pos, decw, decb, h32, hb);

  for (int l = 0; l < 8; ++l) {
    const size_t lo1 = (size_t)l * 3072 * 1024;
    const size_t lo2 = (size_t)l * 1024 * 1024;
    const size_t lo3 = (size_t)l * 4096 * 1024;

    f2b_conv<<<1536, 256, 0, stream>>>(qkvw + lo1, wq,  3072*1024/8);
    f2b_conv<<< 512, 256, 0, stream>>>(apw  + lo2, wap, 1024*1024/8);
    f2b_conv<<<2048, 256, 0, stream>>>(fcw  + lo3, wfc, 4096*1024/8);
    f2b_conv<<<2048, 256, 0, stream>>>(mpw  + lo3, wmp, 4096*1024/8);

    gemm_lds<128,1,0><<<dim3(24,16), 256, 0, stream>>>(hb, wq, qkvb + (size_t)l*3072, qkvB, 2048, 3072, 1024);
    attn_fwd<<<dim3(8,32), 256, 0, stream>>>(qkvB, ab);
    gemm_lds< 64,0,0><<<dim3(16,16), 256, 0, stream>>>(ab, wap, apb + (size_t)l*1024, p32, 2048, 1024, 1024);
    ln_row<<<2048, 256, 0, stream>>>(p32, h32, l1w + (size_t)l*1024, l1b + (size_t)l*1024, h32, hb);
    gemm_lds<128,1,1><<<dim3(32,16), 256, 0, stream>>>(hb, wfc, fcb + (size_t)l*4096, fb, 2048, 4096, 1024);
    gemm_lds< 64,0,0><<<dim3(16,16), 256, 0, stream>>>(fb, wmp, mpb + (size_t)l*1024, p32, 2048, 1024, 4096);
    ln_row<<<2048, 256, 0, stream>>>(p32, h32, l2w + (size_t)l*1024, l2b + (size_t)l*1024, h32, hb);
  }

  ln_row<<<2048, 256, 0, stream>>>(h32, nullptr, finw, finb, out, nullptr);
}

// Round 3
// 1823.891 us; speedup vs baseline: 1.6164x; 1.0251x over previous
//
#include <hip/hip_runtime.h>
#include <hip/hip_bf16.h>

#define E 1024
#define SLEN 1024
#define QKV3 3072
#define HD 64

typedef unsigned short u16;
typedef unsigned int   u32;
typedef __bf16 bf16x8 __attribute__((ext_vector_type(8)));
typedef float  f32x4  __attribute__((ext_vector_type(4)));

__device__ __forceinline__ u16 f2bf(float f) {
  __hip_bfloat16 h = __float2bfloat16(f);
  return __builtin_bit_cast(u16, h);
}
__device__ __forceinline__ u32 pk2(float a, float b) {
  return (u32)f2bf(a) | ((u32)f2bf(b) << 16);
}
__device__ __forceinline__ uint4 pack8(const float4& x, const float4& y) {
  return make_uint4(pk2(x.x,x.y), pk2(x.z,x.w), pk2(y.x,y.y), pk2(y.z,y.w));
}

// async global->LDS, 16B per lane; LDS dest = wave-uniform base + lane*16
__device__ __forceinline__ void gload16(const u16* g, u16* l) {
  __builtin_amdgcn_global_load_lds(
      (const __attribute__((address_space(1))) void*)g,
      (__attribute__((address_space(3))) void*)l, 16, 0, 0);
}

// P-buffer granule swizzle (attention, verified round 1)
__device__ __forceinline__ int swzP(int row, int ch) { return (row<<4) + (ch ^ (row & 7)); }

// ---------------- f32 -> bf16 convert (all-layers weight pre-pass) ----------
__global__ __launch_bounds__(256)
void f2b_conv(const float* __restrict__ src, u16* __restrict__ dst, int n8)
{
  const int stride = gridDim.x * 256;
  for (int i = blockIdx.x * 256 + threadIdx.x; i < n8; i += stride) {
    const float4 a = ((const float4*)src)[i*2];
    const float4 b = ((const float4*)src)[i*2+1];
    ((uint4*)dst)[i] = pack8(a, b);
  }
}

// ---------------- GEMM (m97 structure): C = A[M][K] @ W[N][K]^T + bias -------
// bf16 A,W via global_load_lds; BM=128, BK=32, 256 threads (2x2 waves),
// double-buffered linear LDS. SK>1: split-K partial planes (f32, bias on z==0).
template<int BN, int OUTBF, int GELU, int SK>
__global__ __launch_bounds__(256)
void gemm_lds(const u16* __restrict__ A, const u16* __restrict__ W,
              const float* __restrict__ bias, void* __restrict__ Cv,
              int M, int N, int K)
{
  static_assert(!(GELU && SK > 1), "gelu needs full sum");
  static_assert(!(OUTBF && SK > 1), "partials are f32");
  constexpr int BM = 128;
  __shared__ __align__(16) u16 sA[2][BM*32];
  __shared__ __align__(16) u16 sB[2][BN*32];

  const int t = threadIdx.x;
  const int lane = t & 63;
  const int w = t >> 6;
  const int r = lane & 15;
  const int g = lane >> 4;
  const int wr = (w >> 1) * 64;
  const int wc = (w & 1) * (BN/2);

  const int row0 = blockIdx.y * BM;
  const int col0 = blockIdx.x * BN;
  const int k0   = (SK > 1) ? (int)blockIdx.z * (K / SK) : 0;

  constexpr int ACH = BM/16;
  constexpr int NCH = ACH + BN/16;
  constexpr int CPW = NCH/4;

  const int lrow = lane >> 2;
  const int lcol = (lane & 3) << 3;

  f32x4 acc[4][BN/32];
  #pragma unroll
  for (int i=0;i<4;i++)
    #pragma unroll
    for (int j=0;j<BN/32;j++)
      acc[i][j] = f32x4{0.f,0.f,0.f,0.f};

  const int nk = (K / SK) >> 5;

  auto stage = [&](int kt, int buf) {
    #pragma unroll
    for (int i = 0; i < CPW; ++i) {
      const int c = w*CPW + i;
      if (c < ACH) {
        const u16* gp = A + (size_t)(row0 + c*16 + lrow) * K + k0 + (kt<<5) + lcol;
        gload16(gp, &sA[buf][c*512]);
      } else {
        const int cb = c - ACH;
        const u16* gp = W + (size_t)(col0 + cb*16 + lrow) * K + k0 + (kt<<5) + lcol;
        gload16(gp, &sB[buf][cb*512]);
      }
    }
  };

  stage(0, 0);

  for (int kt = 0; kt < nk; ++kt) {
    const int cur = kt & 1;
    __syncthreads();
    if (kt + 1 < nk) stage(kt + 1, cur ^ 1);

    bf16x8 af[4], bfr[BN/32];
    #pragma unroll
    for (int m=0;m<4;m++)
      af[m] = *(const bf16x8*)&sA[cur][(wr + (m<<4) + r)*32 + (g<<3)];
    #pragma unroll
    for (int n=0;n<BN/32;n++)
      bfr[n] = *(const bf16x8*)&sB[cur][(wc + (n<<4) + r)*32 + (g<<3)];
    #pragma unroll
    for (int m=0;m<4;m++)
      #pragma unroll
      for (int n=0;n<BN/32;n++)
        acc[m][n] = __builtin_amdgcn_mfma_f32_16x16x32_bf16(af[m], bfr[n], acc[m][n], 0, 0, 0);
  }

  float* C32 = (float*)Cv + ((SK > 1) ? (size_t)blockIdx.z * M * N : 0);

  #pragma unroll
  for (int n=0;n<BN/32;n++) {
    const int col = col0 + wc + (n<<4) + r;
    const float bv = (SK == 1 || blockIdx.z == 0) ? bias[col] : 0.f;
    #pragma unroll
    for (int m=0;m<4;m++) {
      const int rowb = row0 + wr + (m<<4) + (g<<2);
      #pragma unroll
      for (int q=0;q<4;q++) {
        float v = acc[m][n][q] + bv;
        if (GELU) v = 0.5f * v * (1.f + erff(v * 0.70710678118f));
        if (OUTBF) ((u16*)Cv)[(size_t)(rowb + q) * N + col] = f2bf(v);
        else       C32[(size_t)(rowb + q) * N + col] = v;
      }
    }
  }
}

// ---------------- Flash attention (bf16 qkv in, bf16 out) -------------------
__global__ __launch_bounds__(256)
void attn_fwd(const u16* __restrict__ qkv, u16* __restrict__ o)
{
  __shared__ __align__(16) u16 sK[128*64];
  __shared__ __align__(16) u16 sV[64*136];
  __shared__ __align__(16) u16 sP[4*32*128];

  const int qt = blockIdx.x;
  const int bn = blockIdx.y;
  const int b  = bn >> 4;
  const int hd = bn & 15;

  const int t = threadIdx.x;
  const int lane = t & 63;
  const int w = t >> 6;
  const int r = lane & 15;
  const int g = lane >> 4;

  const float SC = 0.125f * 1.44269504089f;

  bf16x8 qf[2][2];
  #pragma unroll
  for (int m=0;m<2;m++)
    #pragma unroll
    for (int kk=0;kk<2;kk++)
      qf[m][kk] = *(const bf16x8*)(qkv + (size_t)(b*SLEN + qt*128 + w*32 + (m<<4) + r) * QKV3
                                   + hd*HD + (kk<<5) + (g<<3));

  float m_run[2][4], l_run[2][4];
  f32x4 aco[2][4];
  #pragma unroll
  for (int m=0;m<2;m++) {
    #pragma unroll
    for (int q=0;q<4;q++) { m_run[m][q] = -1e30f; l_run[m][q] = 0.f; }
    #pragma unroll
    for (int n=0;n<4;n++) aco[m][n] = f32x4{0.f,0.f,0.f,0.f};
  }

  u16* sPw = sP + (w << 12);

  const int nkt = qt + 1;
  for (int kt = 0; kt < nkt; ++kt) {
    __syncthreads();
    {
      const int rl = lane >> 3;
      const int hc = (lane & 7) ^ rl;
      #pragma unroll
      for (int i=0;i<4;i++) {
        const int c = w*4 + i;
        const u16* gp = qkv + (size_t)(b*SLEN + kt*128 + c*8 + rl) * QKV3
                      + E + hd*HD + (hc<<3);
        gload16(gp, &sK[c*512]);
      }
    }
    {
      const int vh = t & 63;
      const int tb = (t >> 6) << 5;
      const u16* vp = qkv + (size_t)(b*SLEN + kt*128 + tb) * QKV3 + 2*E + hd*HD + vh;
      #pragma unroll
      for (int i=0;i<32;i+=2) {
        const u32 v0 = vp[(size_t)i * QKV3];
        const u32 v1 = vp[(size_t)(i+1) * QKV3];
        const int tt = tb + i;
        const int gran = vh*17 + (tt >> 3);
        *(u32*)&sV[(gran<<3) + (tt & 7)] = v0 | (v1 << 16);
      }
    }
    __syncthreads();

    f32x4 s[2][8];
    #pragma unroll
    for (int m=0;m<2;m++)
      #pragma unroll
      for (int n=0;n<8;n++)
        s[m][n] = f32x4{0.f,0.f,0.f,0.f};
    #pragma unroll
    for (int kk=0;kk<2;kk++) {
      bf16x8 kf[8];
      #pragma unroll
      for (int n=0;n<8;n++)
        kf[n] = *(const bf16x8*)&sK[((n<<4)+r)*64 + ((((kk<<2)+g) ^ (r&7))<<3)];
      #pragma unroll
      for (int m=0;m<2;m++)
        #pragma unroll
        for (int n=0;n<8;n++)
          s[m][n] = __builtin_amdgcn_mfma_f32_16x16x32_bf16(qf[m][kk], kf[n], s[m][n], 0,0,0);
    }
    #pragma unroll
    for (int m=0;m<2;m++)
      #pragma unroll
      for (int n=0;n<8;n++)
        #pragma unroll
        for (int q=0;q<4;q++)
          s[m][n][q] *= SC;

    if (kt == qt) {
      #pragma unroll
      for (int m=0;m<2;m++)
        #pragma unroll
        for (int n=0;n<8;n++) {
          const int tg = (n<<4) + r;
          #pragma unroll
          for (int q=0;q<4;q++) {
            const int qg = w*32 + (m<<4) + (g<<2) + q;
            if (tg > qg) s[m][n][q] = -1e30f;
          }
        }
    }

    #pragma unroll
    for (int m=0;m<2;m++) {
      float f[4], rs[4];
      #pragma unroll
      for (int q=0;q<4;q++) {
        float v = s[m][0][q];
        #pragma unroll
        for (int n=1;n<8;n++) v = fmaxf(v, s[m][n][q]);
        v = fmaxf(v, __shfl_xor(v, 1));
        v = fmaxf(v, __shfl_xor(v, 2));
        v = fmaxf(v, __shfl_xor(v, 4));
        v = fmaxf(v, __shfl_xor(v, 8));
        const float mn = fmaxf(m_run[m][q], v);
        f[q] = exp2f(m_run[m][q] - mn);
        m_run[m][q] = mn;
        rs[q] = 0.f;
      }
      #pragma unroll
      for (int n=0;n<8;n++) {
        #pragma unroll
        for (int q=0;q<4;q++) {
          const float p = exp2f(s[m][n][q] - m_run[m][q]);
          rs[q] += p;
          const int prow = (m<<4) + (g<<2) + q;
          const int pch = (n<<1) + (r>>3);
          sPw[(swzP(prow, pch)<<3) + (r&7)] = f2bf(p);
        }
      }
      #pragma unroll
      for (int q=0;q<4;q++) {
        rs[q] += __shfl_xor(rs[q], 1);
        rs[q] += __shfl_xor(rs[q], 2);
        rs[q] += __shfl_xor(rs[q], 4);
        rs[q] += __shfl_xor(rs[q], 8);
        l_run[m][q] = l_run[m][q]*f[q] + rs[q];
      }
      #pragma unroll
      for (int n=0;n<4;n++)
        #pragma unroll
        for (int q=0;q<4;q++)
          aco[m][n][q] *= f[q];
    }

    __builtin_amdgcn_s_waitcnt(0);
    __builtin_amdgcn_sched_barrier(0);

    #pragma unroll
    for (int kk=0;kk<4;kk++) {
      bf16x8 pf[2], vf[4];
      #pragma unroll
      for (int m=0;m<2;m++)
        pf[m] = *(const bf16x8*)&sPw[swzP((m<<4)+r, (kk<<2)+g)<<3];
      #pragma unroll
      for (int n=0;n<4;n++)
        vf[n] = *(const bf16x8*)&sV[(((n<<4)+r)*17 + (kk<<2) + g)<<3];
      #pragma unroll
      for (int m=0;m<2;m++)
        #pragma unroll
        for (int n=0;n<4;n++)
          aco[m][n] = __builtin_amdgcn_mfma_f32_16x16x32_bf16(pf[m], vf[n], aco[m][n], 0,0,0);
    }
  }

  #pragma unroll
  for (int m=0;m<2;m++)
    #pragma unroll
    for (int n=0;n<4;n++) {
      const int col = hd*HD + (n<<4) + r;
      #pragma unroll
      for (int q=0;q<4;q++) {
        const int qg = qt*128 + w*32 + (m<<4) + (g<<2) + q;
        o[(size_t)(b*SLEN + qg) * E + col] = f2bf(aco[m][n][q] / l_run[m][q]);
      }
    }
}

// -------- LayerNorm over (a [+ a2] [+ res]), dual f32/bf16 outputs ----------
__global__ __launch_bounds__(256)
void ln_row(const float* __restrict__ a, const float* __restrict__ a2,
            const float* __restrict__ res,
            const float* __restrict__ lw, const float* __restrict__ lb,
            float* __restrict__ out32, u16* __restrict__ outb)
{
  __shared__ float red[8];
  const int row = blockIdx.x;
  const int i = threadIdx.x;
  float4 v = ((const float4*)(a + ((size_t)row << 10)))[i];
  if (a2 != nullptr) {
    const float4 rv = ((const float4*)(a2 + ((size_t)row << 10)))[i];
    v.x += rv.x; v.y += rv.y; v.z += rv.z; v.w += rv.w;
  }
  if (res != nullptr) {
    const float4 rv = ((const float4*)(res + ((size_t)row << 10)))[i];
    v.x += rv.x; v.y += rv.y; v.z += rv.z; v.w += rv.w;
  }
  float s1 = v.x + v.y + v.z + v.w;
  float s2 = v.x*v.x + v.y*v.y + v.z*v.z + v.w*v.w;
  #pragma unroll
  for (int off=1; off<64; off<<=1) { s1 += __shfl_xor(s1, off); s2 += __shfl_xor(s2, off); }
  if ((i & 63) == 0) { red[(i>>6)*2] = s1; red[(i>>6)*2+1] = s2; }
  __syncthreads();
  s1 = red[0] + red[2] + red[4] + red[6];
  s2 = red[1] + red[3] + red[5] + red[7];
  const float mean = s1 * (1.f/1024.f);
  const float var  = s2 * (1.f/1024.f) - mean*mean;
  const float rstd = rsqrtf(var + 1e-5f);
  const float4 wv = ((const float4*)lw)[i];
  const float4 bv = ((const float4*)lb)[i];
  float4 ov;
  ov.x = (v.x - mean)*rstd*wv.x + bv.x;
  ov.y = (v.y - mean)*rstd*wv.y + bv.y;
  ov.z = (v.z - mean)*rstd*wv.z + bv.z;
  ov.w = (v.w - mean)*rstd*wv.w + bv.w;
  if (out32) ((float4*)(out32 + ((size_t)row << 10)))[i] = ov;
  if (outb) {
    uint2 pk; pk.x = pk2(ov.x, ov.y); pk.y = pk2(ov.z, ov.w);
    ((uint2*)(outb + ((size_t)row << 10)))[i] = pk;
  }
}

// ---------------- Embedding + decoder LN, dual outputs ----------------------
__global__ __launch_bounds__(256)
void embed_ln(const int* __restrict__ x, const float* __restrict__ tok,
              const float* __restrict__ pos, const float* __restrict__ lw,
              const float* __restrict__ lb, float* __restrict__ h32,
              u16* __restrict__ hb)
{
  __shared__ float red[8];
  const int row = blockIdx.x;
  const int s = row & (SLEN-1);
  const int i = threadIdx.x;
  const int id = x[row];
  const float4 tv = ((const float4*)(tok + ((size_t)id << 10)))[i];
  const float4 pv = ((const float4*)(pos + ((size_t)s << 10)))[i];
  float4 v;
  v.x = tv.x + pv.x; v.y = tv.y + pv.y; v.z = tv.z + pv.z; v.w = tv.w + pv.w;
  float s1 = v.x + v.y + v.z + v.w;
  float s2 = v.x*v.x + v.y*v.y + v.z*v.z + v.w*v.w;
  #pragma unroll
  for (int off=1; off<64; off<<=1) { s1 += __shfl_xor(s1, off); s2 += __shfl_xor(s2, off); }
  if ((i & 63) == 0) { red[(i>>6)*2] = s1; red[(i>>6)*2+1] = s2; }
  __syncthreads();
  s1 = red[0] + red[2] + red[4] + red[6];
  s2 = red[1] + red[3] + red[5] + red[7];
  const float mean = s1 * (1.f/1024.f);
  const float var  = s2 * (1.f/1024.f) - mean*mean;
  const float rstd = rsqrtf(var + 1e-5f);
  const float4 wv = ((const float4*)lw)[i];
  const float4 bv = ((const float4*)lb)[i];
  float4 ov;
  ov.x = (v.x - mean)*rstd*wv.x + bv.x;
  ov.y = (v.y - mean)*rstd*wv.y + bv.y;
  ov.z = (v.z - mean)*rstd*wv.z + bv.z;
  ov.w = (v.w - mean)*rstd*wv.w + bv.w;
  ((float4*)(h32 + ((size_t)row << 10)))[i] = ov;
  uint2 pk; pk.x = pk2(ov.x, ov.y); pk.y = pk2(ov.z, ov.w);
  ((uint2*)(hb + ((size_t)row << 10)))[i] = pk;
}

extern "C" void kernel_launch(void* const* d_in, const int* in_sizes, int n_in,
                              void* d_out, int out_size, void* d_ws, size_t ws_size,
                              hipStream_t stream) {
  const int*   x    = (const int*)  d_in[0];
  const float* tok  = (const float*)d_in[1];
  const float* pos  = (const float*)d_in[2];
  const float* decw = (const float*)d_in[3];
  const float* decb = (const float*)d_in[4];
  const float* qkvw = (const float*)d_in[5];
  const float* qkvb = (const float*)d_in[6];
  const float* apw  = (const float*)d_in[7];
  const float* apb  = (const float*)d_in[8];
  const float* l1w  = (const float*)d_in[9];
  const float* l1b  = (const float*)d_in[10];
  const float* fcw  = (const float*)d_in[11];
  const float* fcb  = (const float*)d_in[12];
  const float* mpw  = (const float*)d_in[13];
  const float* mpb  = (const float*)d_in[14];
  const float* l2w  = (const float*)d_in[15];
  const float* l2b  = (const float*)d_in[16];
  const float* finw = (const float*)d_in[17];
  const float* finb = (const float*)d_in[18];
  float* out = (float*)d_out;

  // workspace (~270 MB of the ~800 MB available)
  char* p = (char*)d_ws;
  float* h32  = (float*)p;                 p += (size_t)2048*1024*4;     // 8 MB
  float* part = (float*)p;                 p += (size_t)2*2048*1024*4;   // 16 MB (split-K planes)
  u16*   hb   = (u16*)p;                   p += (size_t)2048*1024*2;     // 4 MB
  u16*   qkvB = (u16*)p;                   p += (size_t)2048*3072*2;     // 12 MB
  u16*   ab   = (u16*)p;                   p += (size_t)2048*1024*2;     // 4 MB
  u16*   fb   = (u16*)p;                   p += (size_t)2048*4096*2;     // 16 MB
  u16*   wq   = (u16*)p;                   p += (size_t)8*3072*1024*2;   // 48 MB
  u16*   wap  = (u16*)p;                   p += (size_t)8*1024*1024*2;   // 16 MB
  u16*   wfc  = (u16*)p;                   p += (size_t)8*4096*1024*2;   // 64 MB
  u16*   wmp  = (u16*)p;                   p += (size_t)8*4096*1024*2;   // 64 MB
  float* part1 = part + (size_t)2048*1024;

  // all-layer weight conversion up front (4 dispatches)
  f2b_conv<<<4096, 256, 0, stream>>>(qkvw, wq,  8*3072*1024/8);
  f2b_conv<<<4096, 256, 0, stream>>>(apw,  wap, 8*1024*1024/8);
  f2b_conv<<<4096, 256, 0, stream>>>(fcw,  wfc, 8*4096*1024/8);
  f2b_conv<<<4096, 256, 0, stream>>>(mpw,  wmp, 8*4096*1024/8);

  embed_ln<<<2048, 256, 0, stream>>>(x, tok, pos, decw, decb, h32, hb);

  for (int l = 0; l < 8; ++l) {
    const u16* lwq  = wq  + (size_t)l*3072*1024;
    const u16* lwap = wap + (size_t)l*1024*1024;
    const u16* lwfc = wfc + (size_t)l*4096*1024;
    const u16* lwmp = wmp + (size_t)l*4096*1024;

    gemm_lds<128,1,0,1><<<dim3(24,16),   256, 0, stream>>>(hb, lwq,  qkvb + (size_t)l*3072, qkvB, 2048, 3072, 1024);
    attn_fwd<<<dim3(8,32), 256, 0, stream>>>(qkvB, ab);
    gemm_lds<128,0,0,2><<<dim3(8,16,2),  256, 0, stream>>>(ab, lwap, apb + (size_t)l*1024, part, 2048, 1024, 1024);
    ln_row<<<2048, 256, 0, stream>>>(part, part1, h32, l1w + (size_t)l*1024, l1b + (size_t)l*1024, h32, hb);
    gemm_lds<128,1,1,1><<<dim3(32,16),   256, 0, stream>>>(hb, lwfc, fcb + (size_t)l*4096, fb, 2048, 4096, 1024);
    gemm_lds<128,0,0,2><<<dim3(8,16,2),  256, 0, stream>>>(fb, lwmp, mpb + (size_t)l*1024, part, 2048, 1024, 4096);
    ln_row<<<2048, 256, 0, stream>>>(part, part1, h32, l2w + (size_t)l*1024, l2b + (size_t)l*1024, h32, hb);
  }

  ln_row<<<2048, 256, 0, stream>>>(h32, nullptr, nullptr, finw, finb, out, nullptr);
}

// Round 4
// 1677.516 us; speedup vs baseline: 1.7575x; 1.0873x over previous
//
#include <hip/hip_runtime.h>
#include <hip/hip_bf16.h>

#define E 1024
#define SLEN 1024
#define QKV3 3072
#define HD 64

typedef unsigned short u16;
typedef unsigned int   u32;
typedef __bf16 bf16x8 __attribute__((ext_vector_type(8)));
typedef float  f32x4  __attribute__((ext_vector_type(4)));

__device__ __forceinline__ u16 f2bf(float f) {
  __hip_bfloat16 h = __float2bfloat16(f);
  return __builtin_bit_cast(u16, h);
}
__device__ __forceinline__ u32 pk2(float a, float b) {
  return (u32)f2bf(a) | ((u32)f2bf(b) << 16);
}
__device__ __forceinline__ uint4 pack8(const float4& x, const float4& y) {
  return make_uint4(pk2(x.x,x.y), pk2(x.z,x.w), pk2(y.x,y.y), pk2(y.z,y.w));
}

// async global->LDS, 16B per lane; LDS dest = wave-uniform base + lane*16
__device__ __forceinline__ void gload16(const u16* g, u16* l) {
  __builtin_amdgcn_global_load_lds(
      (const __attribute__((address_space(1))) void*)g,
      (__attribute__((address_space(3))) void*)l, 16, 0, 0);
}

// P-buffer granule swizzle (attention, verified round 1)
__device__ __forceinline__ int swzP(int row, int ch) { return (row<<4) + (ch ^ (row & 7)); }

// ---------------- f32 -> bf16 convert (all-layers weight pre-pass) ----------
__global__ __launch_bounds__(256)
void f2b_conv(const float* __restrict__ src, u16* __restrict__ dst, int n8)
{
  const int stride = gridDim.x * 256;
  for (int i = blockIdx.x * 256 + threadIdx.x; i < n8; i += stride) {
    const float4 a = ((const float4*)src)[i*2];
    const float4 b = ((const float4*)src)[i*2+1];
    ((uint4*)dst)[i] = pack8(a, b);
  }
}

// ---------------- GEMM: C = A[M][K] @ W[N][K]^T + bias ----------------------
// bf16 A,W via global_load_lds; BM=128, BK=32, 256 threads (2x2 waves).
// T3/T4: 3-buffer ring, depth-2 prefetch, counted vmcnt (never 0 mid-loop),
// raw s_barrier (no implicit drain). SK>1: split-K partial planes.
template<int BN, int OUTBF, int GELU, int SK>
__global__ __launch_bounds__(256)
void gemm_lds(const u16* __restrict__ A, const u16* __restrict__ W,
              const float* __restrict__ bias, void* __restrict__ Cv,
              int M, int N, int K)
{
  static_assert(!(GELU && SK > 1), "gelu needs full sum");
  static_assert(!(OUTBF && SK > 1), "partials are f32");
  constexpr int BM = 128;
  __shared__ __align__(16) u16 sA[3][BM*32];
  __shared__ __align__(16) u16 sB[3][BN*32];

  const int t = threadIdx.x;
  const int lane = t & 63;
  const int w = t >> 6;
  const int r = lane & 15;
  const int g = lane >> 4;
  const int wr = (w >> 1) * 64;
  const int wc = (w & 1) * (BN/2);

  const int row0 = blockIdx.y * BM;
  const int col0 = blockIdx.x * BN;
  const int k0   = (SK > 1) ? (int)blockIdx.z * (K / SK) : 0;

  constexpr int ACH = BM/16;            // A chunks (1 KB each)
  constexpr int NCH = ACH + BN/16;
  constexpr int CPW = NCH/4;            // gloads per wave per stage (=4 at BN=128)

  const int lrow = lane >> 2;
  const int lcol = (lane & 3) << 3;

  f32x4 acc[4][BN/32];
  #pragma unroll
  for (int i=0;i<4;i++)
    #pragma unroll
    for (int j=0;j<BN/32;j++)
      acc[i][j] = f32x4{0.f,0.f,0.f,0.f};

  const int nk = (K / SK) >> 5;

  auto stage = [&](int kt, int buf) {
    #pragma unroll
    for (int i = 0; i < CPW; ++i) {
      const int c = w*CPW + i;
      if (c < ACH) {
        const u16* gp = A + (size_t)(row0 + c*16 + lrow) * K + k0 + (kt<<5) + lcol;
        gload16(gp, &sA[buf][c*512]);
      } else {
        const int cb = c - ACH;
        const u16* gp = W + (size_t)(col0 + cb*16 + lrow) * K + k0 + (kt<<5) + lcol;
        gload16(gp, &sB[buf][cb*512]);
      }
    }
  };

  stage(0, 0);
  if (nk > 1) stage(1, 1);

  int cur = 0;
  for (int kt = 0; kt < nk; ++kt) {
    // wait only for the OLDEST stage (kt) to land; stage kt+1 stays in flight
    if (kt + 1 < nk) asm volatile("s_waitcnt vmcnt(4)" ::: "memory");
    else             asm volatile("s_waitcnt vmcnt(0)" ::: "memory");
    __builtin_amdgcn_s_barrier();   // all waves landed their stage(kt); all done reading buf[kt-1]

    if (kt + 2 < nk) stage(kt + 2, (cur + 2 >= 3) ? cur - 1 : cur + 2);

    bf16x8 af[4], bfr[BN/32];
    #pragma unroll
    for (int m=0;m<4;m++)
      af[m] = *(const bf16x8*)&sA[cur][(wr + (m<<4) + r)*32 + (g<<3)];
    #pragma unroll
    for (int n=0;n<BN/32;n++)
      bfr[n] = *(const bf16x8*)&sB[cur][(wc + (n<<4) + r)*32 + (g<<3)];
    #pragma unroll
    for (int m=0;m<4;m++)
      #pragma unroll
      for (int n=0;n<BN/32;n++)
        acc[m][n] = __builtin_amdgcn_mfma_f32_16x16x32_bf16(af[m], bfr[n], acc[m][n], 0, 0, 0);

    cur = (cur + 1 >= 3) ? 0 : cur + 1;
  }

  float* C32 = (float*)Cv + ((SK > 1) ? (size_t)blockIdx.z * M * N : 0);

  #pragma unroll
  for (int n=0;n<BN/32;n++) {
    const int col = col0 + wc + (n<<4) + r;
    const float bv = (SK == 1 || blockIdx.z == 0) ? bias[col] : 0.f;
    #pragma unroll
    for (int m=0;m<4;m++) {
      const int rowb = row0 + wr + (m<<4) + (g<<2);
      #pragma unroll
      for (int q=0;q<4;q++) {
        float v = acc[m][n][q] + bv;
        if (GELU) v = 0.5f * v * (1.f + erff(v * 0.70710678118f));
        if (OUTBF) ((u16*)Cv)[(size_t)(rowb + q) * N + col] = f2bf(v);
        else       C32[(size_t)(rowb + q) * N + col] = v;
      }
    }
  }
}

// ---------------- Flash attention (bf16 qkv in, bf16 out) -------------------
__global__ __launch_bounds__(256)
void attn_fwd(const u16* __restrict__ qkv, u16* __restrict__ o)
{
  __shared__ __align__(16) u16 sK[128*64];
  __shared__ __align__(16) u16 sV[64*136];
  __shared__ __align__(16) u16 sP[4*32*128];

  const int qt = blockIdx.x;
  const int bn = blockIdx.y;
  const int b  = bn >> 4;
  const int hd = bn & 15;

  const int t = threadIdx.x;
  const int lane = t & 63;
  const int w = t >> 6;
  const int r = lane & 15;
  const int g = lane >> 4;

  const float SC = 0.125f * 1.44269504089f;

  bf16x8 qf[2][2];
  #pragma unroll
  for (int m=0;m<2;m++)
    #pragma unroll
    for (int kk=0;kk<2;kk++)
      qf[m][kk] = *(const bf16x8*)(qkv + (size_t)(b*SLEN + qt*128 + w*32 + (m<<4) + r) * QKV3
                                   + hd*HD + (kk<<5) + (g<<3));

  float m_run[2][4], l_run[2][4];
  f32x4 aco[2][4];
  #pragma unroll
  for (int m=0;m<2;m++) {
    #pragma unroll
    for (int q=0;q<4;q++) { m_run[m][q] = -1e30f; l_run[m][q] = 0.f; }
    #pragma unroll
    for (int n=0;n<4;n++) aco[m][n] = f32x4{0.f,0.f,0.f,0.f};
  }

  u16* sPw = sP + (w << 12);

  const int nkt = qt + 1;
  for (int kt = 0; kt < nkt; ++kt) {
    __syncthreads();
    {
      const int rl = lane >> 3;
      const int hc = (lane & 7) ^ rl;
      #pragma unroll
      for (int i=0;i<4;i++) {
        const int c = w*4 + i;
        const u16* gp = qkv + (size_t)(b*SLEN + kt*128 + c*8 + rl) * QKV3
                      + E + hd*HD + (hc<<3);
        gload16(gp, &sK[c*512]);
      }
    }
    {
      const int vh = t & 63;
      const int tb = (t >> 6) << 5;
      const u16* vp = qkv + (size_t)(b*SLEN + kt*128 + tb) * QKV3 + 2*E + hd*HD + vh;
      #pragma unroll
      for (int i=0;i<32;i+=2) {
        const u32 v0 = vp[(size_t)i * QKV3];
        const u32 v1 = vp[(size_t)(i+1) * QKV3];
        const int tt = tb + i;
        const int gran = vh*17 + (tt >> 3);
        *(u32*)&sV[(gran<<3) + (tt & 7)] = v0 | (v1 << 16);
      }
    }
    __syncthreads();

    f32x4 s[2][8];
    #pragma unroll
    for (int m=0;m<2;m++)
      #pragma unroll
      for (int n=0;n<8;n++)
        s[m][n] = f32x4{0.f,0.f,0.f,0.f};
    #pragma unroll
    for (int kk=0;kk<2;kk++) {
      bf16x8 kf[8];
      #pragma unroll
      for (int n=0;n<8;n++)
        kf[n] = *(const bf16x8*)&sK[((n<<4)+r)*64 + ((((kk<<2)+g) ^ (r&7))<<3)];
      #pragma unroll
      for (int m=0;m<2;m++)
        #pragma unroll
        for (int n=0;n<8;n++)
          s[m][n] = __builtin_amdgcn_mfma_f32_16x16x32_bf16(qf[m][kk], kf[n], s[m][n], 0,0,0);
    }
    #pragma unroll
    for (int m=0;m<2;m++)
      #pragma unroll
      for (int n=0;n<8;n++)
        #pragma unroll
        for (int q=0;q<4;q++)
          s[m][n][q] *= SC;

    if (kt == qt) {
      #pragma unroll
      for (int m=0;m<2;m++)
        #pragma unroll
        for (int n=0;n<8;n++) {
          const int tg = (n<<4) + r;
          #pragma unroll
          for (int q=0;q<4;q++) {
            const int qg = w*32 + (m<<4) + (g<<2) + q;
            if (tg > qg) s[m][n][q] = -1e30f;
          }
        }
    }

    #pragma unroll
    for (int m=0;m<2;m++) {
      float f[4], rs[4];
      #pragma unroll
      for (int q=0;q<4;q++) {
        float v = s[m][0][q];
        #pragma unroll
        for (int n=1;n<8;n++) v = fmaxf(v, s[m][n][q]);
        v = fmaxf(v, __shfl_xor(v, 1));
        v = fmaxf(v, __shfl_xor(v, 2));
        v = fmaxf(v, __shfl_xor(v, 4));
        v = fmaxf(v, __shfl_xor(v, 8));
        const float mn = fmaxf(m_run[m][q], v);
        f[q] = exp2f(m_run[m][q] - mn);
        m_run[m][q] = mn;
        rs[q] = 0.f;
      }
      #pragma unroll
      for (int n=0;n<8;n++) {
        #pragma unroll
        for (int q=0;q<4;q++) {
          const float p = exp2f(s[m][n][q] - m_run[m][q]);
          rs[q] += p;
          const int prow = (m<<4) + (g<<2) + q;
          const int pch = (n<<1) + (r>>3);
          sPw[(swzP(prow, pch)<<3) + (r&7)] = f2bf(p);
        }
      }
      #pragma unroll
      for (int q=0;q<4;q++) {
        rs[q] += __shfl_xor(rs[q], 1);
        rs[q] += __shfl_xor(rs[q], 2);
        rs[q] += __shfl_xor(rs[q], 4);
        rs[q] += __shfl_xor(rs[q], 8);
        l_run[m][q] = l_run[m][q]*f[q] + rs[q];
      }
      #pragma unroll
      for (int n=0;n<4;n++)
        #pragma unroll
        for (int q=0;q<4;q++)
          aco[m][n][q] *= f[q];
    }

    __builtin_amdgcn_s_waitcnt(0);
    __builtin_amdgcn_sched_barrier(0);

    #pragma unroll
    for (int kk=0;kk<4;kk++) {
      bf16x8 pf[2], vf[4];
      #pragma unroll
      for (int m=0;m<2;m++)
        pf[m] = *(const bf16x8*)&sPw[swzP((m<<4)+r, (kk<<2)+g)<<3];
      #pragma unroll
      for (int n=0;n<4;n++)
        vf[n] = *(const bf16x8*)&sV[(((n<<4)+r)*17 + (kk<<2) + g)<<3];
      #pragma unroll
      for (int m=0;m<2;m++)
        #pragma unroll
        for (int n=0;n<4;n++)
          aco[m][n] = __builtin_amdgcn_mfma_f32_16x16x32_bf16(pf[m], vf[n], aco[m][n], 0,0,0);
    }
  }

  #pragma unroll
  for (int m=0;m<2;m++)
    #pragma unroll
    for (int n=0;n<4;n++) {
      const int col = hd*HD + (n<<4) + r;
      #pragma unroll
      for (int q=0;q<4;q++) {
        const int qg = qt*128 + w*32 + (m<<4) + (g<<2) + q;
        o[(size_t)(b*SLEN + qg) * E + col] = f2bf(aco[m][n][q] / l_run[m][q]);
      }
    }
}

// -------- LayerNorm over (a [+ a2] [+ res]), dual f32/bf16 outputs ----------
__global__ __launch_bounds__(256)
void ln_row(const float* __restrict__ a, const float* __restrict__ a2,
            const float* __restrict__ res,
            const float* __restrict__ lw, const float* __restrict__ lb,
            float* __restrict__ out32, u16* __restrict__ outb)
{
  __shared__ float red[8];
  const int row = blockIdx.x;
  const int i = threadIdx.x;
  float4 v = ((const float4*)(a + ((size_t)row << 10)))[i];
  if (a2 != nullptr) {
    const float4 rv = ((const float4*)(a2 + ((size_t)row << 10)))[i];
    v.x += rv.x; v.y += rv.y; v.z += rv.z; v.w += rv.w;
  }
  if (res != nullptr) {
    const float4 rv = ((const float4*)(res + ((size_t)row << 10)))[i];
    v.x += rv.x; v.y += rv.y; v.z += rv.z; v.w += rv.w;
  }
  float s1 = v.x + v.y + v.z + v.w;
  float s2 = v.x*v.x + v.y*v.y + v.z*v.z + v.w*v.w;
  #pragma unroll
  for (int off=1; off<64; off<<=1) { s1 += __shfl_xor(s1, off); s2 += __shfl_xor(s2, off); }
  if ((i & 63) == 0) { red[(i>>6)*2] = s1; red[(i>>6)*2+1] = s2; }
  __syncthreads();
  s1 = red[0] + red[2] + red[4] + red[6];
  s2 = red[1] + red[3] + red[5] + red[7];
  const float mean = s1 * (1.f/1024.f);
  const float var  = s2 * (1.f/1024.f) - mean*mean;
  const float rstd = rsqrtf(var + 1e-5f);
  const float4 wv = ((const float4*)lw)[i];
  const float4 bv = ((const float4*)lb)[i];
  float4 ov;
  ov.x = (v.x - mean)*rstd*wv.x + bv.x;
  ov.y = (v.y - mean)*rstd*wv.y + bv.y;
  ov.z = (v.z - mean)*rstd*wv.z + bv.z;
  ov.w = (v.w - mean)*rstd*wv.w + bv.w;
  if (out32) ((float4*)(out32 + ((size_t)row << 10)))[i] = ov;
  if (outb) {
    uint2 pk; pk.x = pk2(ov.x, ov.y); pk.y = pk2(ov.z, ov.w);
    ((uint2*)(outb + ((size_t)row << 10)))[i] = pk;
  }
}

// ---------------- Embedding + decoder LN, dual outputs ----------------------
__global__ __launch_bounds__(256)
void embed_ln(const int* __restrict__ x, const float* __restrict__ tok,
              const float* __restrict__ pos, const float* __restrict__ lw,
              const float* __restrict__ lb, float* __restrict__ h32,
              u16* __restrict__ hb)
{
  __shared__ float red[8];
  const int row = blockIdx.x;
  const int s = row & (SLEN-1);
  const int i = threadIdx.x;
  const int id = x[row];
  const float4 tv = ((const float4*)(tok + ((size_t)id << 10)))[i];
  const float4 pv = ((const float4*)(pos + ((size_t)s << 10)))[i];
  float4 v;
  v.x = tv.x + pv.x; v.y = tv.y + pv.y; v.z = tv.z + pv.z; v.w = tv.w + pv.w;
  float s1 = v.x + v.y + v.z + v.w;
  float s2 = v.x*v.x + v.y*v.y + v.z*v.z + v.w*v.w;
  #pragma unroll
  for (int off=1; off<64; off<<=1) { s1 += __shfl_xor(s1, off); s2 += __shfl_xor(s2, off); }
  if ((i & 63) == 0) { red[(i>>6)*2] = s1; red[(i>>6)*2+1] = s2; }
  __syncthreads();
  s1 = red[0] + red[2] + red[4] + red[6];
  s2 = red[1] + red[3] + red[5] + red[7];
  const float mean = s1 * (1.f/1024.f);
  const float var  = s2 * (1.f/1024.f) - mean*mean;
  const float rstd = rsqrtf(var + 1e-5f);
  const float4 wv = ((const float4*)lw)[i];
  const float4 bv = ((const float4*)lb)[i];
  float4 ov;
  ov.x = (v.x - mean)*rstd*wv.x + bv.x;
  ov.y = (v.y - mean)*rstd*wv.y + bv.y;
  ov.z = (v.z - mean)*rstd*wv.z + bv.z;
  ov.w = (v.w - mean)*rstd*wv.w + bv.w;
  ((float4*)(h32 + ((size_t)row << 10)))[i] = ov;
  uint2 pk; pk.x = pk2(ov.x, ov.y); pk.y = pk2(ov.z, ov.w);
  ((uint2*)(hb + ((size_t)row << 10)))[i] = pk;
}

extern "C" void kernel_launch(void* const* d_in, const int* in_sizes, int n_in,
                              void* d_out, int out_size, void* d_ws, size_t ws_size,
                              hipStream_t stream) {
  const int*   x    = (const int*)  d_in[0];
  const float* tok  = (const float*)d_in[1];
  const float* pos  = (const float*)d_in[2];
  const float* decw = (const float*)d_in[3];
  const float* decb = (const float*)d_in[4];
  const float* qkvw = (const float*)d_in[5];
  const float* qkvb = (const float*)d_in[6];
  const float* apw  = (const float*)d_in[7];
  const float* apb  = (const float*)d_in[8];
  const float* l1w  = (const float*)d_in[9];
  const float* l1b  = (const float*)d_in[10];
  const float* fcw  = (const float*)d_in[11];
  const float* fcb  = (const float*)d_in[12];
  const float* mpw  = (const float*)d_in[13];
  const float* mpb  = (const float*)d_in[14];
  const float* l2w  = (const float*)d_in[15];
  const float* l2b  = (const float*)d_in[16];
  const float* finw = (const float*)d_in[17];
  const float* finb = (const float*)d_in[18];
  float* out = (float*)d_out;

  // workspace (~270 MB of the ~800 MB available)
  char* p = (char*)d_ws;
  float* h32  = (float*)p;                 p += (size_t)2048*1024*4;     // 8 MB
  float* part = (float*)p;                 p += (size_t)2*2048*1024*4;   // 16 MB (split-K planes)
  u16*   hb   = (u16*)p;                   p += (size_t)2048*1024*2;     // 4 MB
  u16*   qkvB = (u16*)p;                   p += (size_t)2048*3072*2;     // 12 MB
  u16*   ab   = (u16*)p;                   p += (size_t)2048*1024*2;     // 4 MB
  u16*   fb   = (u16*)p;                   p += (size_t)2048*4096*2;     // 16 MB
  u16*   wq   = (u16*)p;                   p += (size_t)8*3072*1024*2;   // 48 MB
  u16*   wap  = (u16*)p;                   p += (size_t)8*1024*1024*2;   // 16 MB
  u16*   wfc  = (u16*)p;                   p += (size_t)8*4096*1024*2;   // 64 MB
  u16*   wmp  = (u16*)p;                   p += (size_t)8*4096*1024*2;   // 64 MB
  float* part1 = part + (size_t)2048*1024;

  // all-layer weight conversion up front (4 dispatches)
  f2b_conv<<<4096, 256, 0, stream>>>(qkvw, wq,  8*3072*1024/8);
  f2b_conv<<<4096, 256, 0, stream>>>(apw,  wap, 8*1024*1024/8);
  f2b_conv<<<4096, 256, 0, stream>>>(fcw,  wfc, 8*4096*1024/8);
  f2b_conv<<<4096, 256, 0, stream>>>(mpw,  wmp, 8*4096*1024/8);

  embed_ln<<<2048, 256, 0, stream>>>(x, tok, pos, decw, decb, h32, hb);

  for (int l = 0; l < 8; ++l) {
    const u16* lwq  = wq  + (size_t)l*3072*1024;
    const u16* lwap = wap + (size_t)l*1024*1024;
    const u16* lwfc = wfc + (size_t)l*4096*1024;
    const u16* lwmp = wmp + (size_t)l*4096*1024;

    gemm_lds<128,1,0,1><<<dim3(24,16),   256, 0, stream>>>(hb, lwq,  qkvb + (size_t)l*3072, qkvB, 2048, 3072, 1024);
    attn_fwd<<<dim3(8,32), 256, 0, stream>>>(qkvB, ab);
    gemm_lds<128,0,0,2><<<dim3(8,16,2),  256, 0, stream>>>(ab, lwap, apb + (size_t)l*1024, part, 2048, 1024, 1024);
    ln_row<<<2048, 256, 0, stream>>>(part, part1, h32, l1w + (size_t)l*1024, l1b + (size_t)l*1024, h32, hb);
    gemm_lds<128,1,1,1><<<dim3(32,16),   256, 0, stream>>>(hb, lwfc, fcb + (size_t)l*4096, fb, 2048, 4096, 1024);
    gemm_lds<128,0,0,2><<<dim3(8,16,2),  256, 0, stream>>>(fb, lwmp, mpb + (size_t)l*1024, part, 2048, 1024, 4096);
    ln_row<<<2048, 256, 0, stream>>>(part, part1, h32, l2w + (size_t)l*1024, l2b + (size_t)l*1024, h32, hb);
  }

  ln_row<<<2048, 256, 0, stream>>>(h32, nullptr, nullptr, finw, finb, out, nullptr);
}

// Round 5
// 1498.732 us; speedup vs baseline: 1.9671x; 1.1193x over previous
//
#include <hip/hip_runtime.h>
#include <hip/hip_bf16.h>

#define E 1024
#define SLEN 1024
#define QKV3 3072
#define HD 64

typedef unsigned short u16;
typedef unsigned int   u32;
typedef __bf16 bf16x8 __attribute__((ext_vector_type(8)));
typedef float  f32x4  __attribute__((ext_vector_type(4)));

__device__ __forceinline__ u16 f2bf(float f) {
  __hip_bfloat16 h = __float2bfloat16(f);
  return __builtin_bit_cast(u16, h);
}
__device__ __forceinline__ u32 pk2(float a, float b) {
  return (u32)f2bf(a) | ((u32)f2bf(b) << 16);
}
__device__ __forceinline__ uint4 pack8(const float4& x, const float4& y) {
  return make_uint4(pk2(x.x,x.y), pk2(x.z,x.w), pk2(y.x,y.y), pk2(y.z,y.w));
}

// async global->LDS, 16B per lane; LDS dest = wave-uniform base + lane*16
__device__ __forceinline__ void gload16(const u16* g, u16* l) {
  __builtin_amdgcn_global_load_lds(
      (const __attribute__((address_space(1))) void*)g,
      (__attribute__((address_space(3))) void*)l, 16, 0, 0);
}

// P-buffer granule swizzle (attention, verified round 1)
__device__ __forceinline__ int swzP(int row, int ch) { return (row<<4) + (ch ^ (row & 7)); }

// ------------- f32 -> bf16 convert, all 4 weight groups in one pass ---------
__global__ __launch_bounds__(256)
void f2b_conv4(const float* __restrict__ s0, u16* __restrict__ d0, int n0,
               const float* __restrict__ s1, u16* __restrict__ d1, int n1,
               const float* __restrict__ s2, u16* __restrict__ d2, int n2,
               const float* __restrict__ s3, u16* __restrict__ d3, int n3)
{
  const int ntot = n0 + n1 + n2 + n3;
  const int stride = gridDim.x * 256;
  for (int i = blockIdx.x * 256 + threadIdx.x; i < ntot; i += stride) {
    const float* s; u16* d; int j = i;
    if (j < n0) { s = s0; d = d0; }
    else if ((j -= n0) < n1) { s = s1; d = d1; }
    else if ((j -= n1) < n2) { s = s2; d = d2; }
    else { j -= n2; s = s3; d = d3; }
    const float4 a = ((const float4*)s)[j*2];
    const float4 b = ((const float4*)s)[j*2+1];
    ((uint4*)d)[j] = pack8(a, b);
  }
}

// ---------------- GEMM: C = A[M][K] @ W[N][K]^T + bias ----------------------
// bf16 A,W via global_load_lds; BM=128, BK=32, 256 threads (2x2 waves).
// T3/T4: 3-buffer ring, depth-2 prefetch, counted vmcnt (never 0 mid-loop),
// raw s_barrier (no implicit drain). SK>1: split-K partial planes.
template<int BN, int OUTBF, int GELU, int SK>
__global__ __launch_bounds__(256)
void gemm_lds(const u16* __restrict__ A, const u16* __restrict__ W,
              const float* __restrict__ bias, void* __restrict__ Cv,
              int M, int N, int K)
{
  static_assert(!(GELU && SK > 1), "gelu needs full sum");
  static_assert(!(OUTBF && SK > 1), "partials are f32");
  constexpr int BM = 128;
  __shared__ __align__(16) u16 sA[3][BM*32];
  __shared__ __align__(16) u16 sB[3][BN*32];

  const int t = threadIdx.x;
  const int lane = t & 63;
  const int w = t >> 6;
  const int r = lane & 15;
  const int g = lane >> 4;
  const int wr = (w >> 1) * 64;
  const int wc = (w & 1) * (BN/2);

  const int row0 = blockIdx.y * BM;
  const int col0 = blockIdx.x * BN;
  const int k0   = (SK > 1) ? (int)blockIdx.z * (K / SK) : 0;

  constexpr int ACH = BM/16;
  constexpr int NCH = ACH + BN/16;
  constexpr int CPW = NCH/4;

  const int lrow = lane >> 2;
  const int lcol = (lane & 3) << 3;

  f32x4 acc[4][BN/32];
  #pragma unroll
  for (int i=0;i<4;i++)
    #pragma unroll
    for (int j=0;j<BN/32;j++)
      acc[i][j] = f32x4{0.f,0.f,0.f,0.f};

  const int nk = (K / SK) >> 5;

  auto stage = [&](int kt, int buf) {
    #pragma unroll
    for (int i = 0; i < CPW; ++i) {
      const int c = w*CPW + i;
      if (c < ACH) {
        const u16* gp = A + (size_t)(row0 + c*16 + lrow) * K + k0 + (kt<<5) + lcol;
        gload16(gp, &sA[buf][c*512]);
      } else {
        const int cb = c - ACH;
        const u16* gp = W + (size_t)(col0 + cb*16 + lrow) * K + k0 + (kt<<5) + lcol;
        gload16(gp, &sB[buf][cb*512]);
      }
    }
  };

  stage(0, 0);
  if (nk > 1) stage(1, 1);

  int cur = 0;
  for (int kt = 0; kt < nk; ++kt) {
    if (kt + 1 < nk) asm volatile("s_waitcnt vmcnt(4)" ::: "memory");
    else             asm volatile("s_waitcnt vmcnt(0)" ::: "memory");
    __builtin_amdgcn_s_barrier();

    if (kt + 2 < nk) stage(kt + 2, (cur + 2 >= 3) ? cur - 1 : cur + 2);

    bf16x8 af[4], bfr[BN/32];
    #pragma unroll
    for (int m=0;m<4;m++)
      af[m] = *(const bf16x8*)&sA[cur][(wr + (m<<4) + r)*32 + (g<<3)];
    #pragma unroll
    for (int n=0;n<BN/32;n++)
      bfr[n] = *(const bf16x8*)&sB[cur][(wc + (n<<4) + r)*32 + (g<<3)];
    #pragma unroll
    for (int m=0;m<4;m++)
      #pragma unroll
      for (int n=0;n<BN/32;n++)
        acc[m][n] = __builtin_amdgcn_mfma_f32_16x16x32_bf16(af[m], bfr[n], acc[m][n], 0, 0, 0);

    cur = (cur + 1 >= 3) ? 0 : cur + 1;
  }

  float* C32 = (float*)Cv + ((SK > 1) ? (size_t)blockIdx.z * M * N : 0);

  #pragma unroll
  for (int n=0;n<BN/32;n++) {
    const int col = col0 + wc + (n<<4) + r;
    const float bv = (SK == 1 || blockIdx.z == 0) ? bias[col] : 0.f;
    #pragma unroll
    for (int m=0;m<4;m++) {
      const int rowb = row0 + wr + (m<<4) + (g<<2);
      #pragma unroll
      for (int q=0;q<4;q++) {
        float v = acc[m][n][q] + bv;
        if (GELU) v = 0.5f * v * (1.f + erff(v * 0.70710678118f));
        if (OUTBF) ((u16*)Cv)[(size_t)(rowb + q) * N + col] = f2bf(v);
        else       C32[(size_t)(rowb + q) * N + col] = v;
      }
    }
  }
}

// ---------------- Flash attention, causal-balanced key-split ----------------
// grid (12 jobs, 32 b*head). Jobs: qt>=4 split into 2 key-range halves
// (partials to ws); qt<4 single block writing bf16 output directly.
__global__ __launch_bounds__(256)
void attn_fwd(const u16* __restrict__ qkv, u16* __restrict__ o,
              float* __restrict__ opart, float* __restrict__ mpart,
              float* __restrict__ lpart)
{
  __shared__ __align__(16) u16 sK[128*64];
  __shared__ __align__(16) u16 sV[64*136];
  __shared__ __align__(16) u16 sP[4*32*128];

  const int j  = blockIdx.x;
  int qt, z, nsplit;
  if (j < 8) { qt = 7 - (j >> 1); z = j & 1; nsplit = 2; }
  else       { qt = 11 - j;       z = 0;     nsplit = 1; }
  const int half = (qt + 1) >> 1;
  const int kt0 = (nsplit == 2 && z == 1) ? half : 0;
  const int kt1 = (nsplit == 2 && z == 0) ? half : qt + 1;

  const int bn = blockIdx.y;
  const int b  = bn >> 4;
  const int hd = bn & 15;

  const int t = threadIdx.x;
  const int lane = t & 63;
  const int w = t >> 6;
  const int r = lane & 15;
  const int g = lane >> 4;

  const float SC = 0.125f * 1.44269504089f;

  bf16x8 qf[2][2];
  #pragma unroll
  for (int m=0;m<2;m++)
    #pragma unroll
    for (int kk=0;kk<2;kk++)
      qf[m][kk] = *(const bf16x8*)(qkv + (size_t)(b*SLEN + qt*128 + w*32 + (m<<4) + r) * QKV3
                                   + hd*HD + (kk<<5) + (g<<3));

  float m_run[2][4], l_run[2][4];
  f32x4 aco[2][4];
  #pragma unroll
  for (int m=0;m<2;m++) {
    #pragma unroll
    for (int q=0;q<4;q++) { m_run[m][q] = -1e30f; l_run[m][q] = 0.f; }
    #pragma unroll
    for (int n=0;n<4;n++) aco[m][n] = f32x4{0.f,0.f,0.f,0.f};
  }

  u16* sPw = sP + (w << 12);

  for (int kt = kt0; kt < kt1; ++kt) {
    __syncthreads();
    {
      const int rl = lane >> 3;
      const int hc = (lane & 7) ^ rl;
      #pragma unroll
      for (int i=0;i<4;i++) {
        const int c = w*4 + i;
        const u16* gp = qkv + (size_t)(b*SLEN + kt*128 + c*8 + rl) * QKV3
                      + E + hd*HD + (hc<<3);
        gload16(gp, &sK[c*512]);
      }
    }
    {
      const int vh = t & 63;
      const int tb = (t >> 6) << 5;
      const u16* vp = qkv + (size_t)(b*SLEN + kt*128 + tb) * QKV3 + 2*E + hd*HD + vh;
      #pragma unroll
      for (int i=0;i<32;i+=2) {
        const u32 v0 = vp[(size_t)i * QKV3];
        const u32 v1 = vp[(size_t)(i+1) * QKV3];
        const int tt = tb + i;
        const int gran = vh*17 + (tt >> 3);
        *(u32*)&sV[(gran<<3) + (tt & 7)] = v0 | (v1 << 16);
      }
    }
    __syncthreads();

    f32x4 s[2][8];
    #pragma unroll
    for (int m=0;m<2;m++)
      #pragma unroll
      for (int n=0;n<8;n++)
        s[m][n] = f32x4{0.f,0.f,0.f,0.f};
    __builtin_amdgcn_s_setprio(1);
    #pragma unroll
    for (int kk=0;kk<2;kk++) {
      bf16x8 kf[8];
      #pragma unroll
      for (int n=0;n<8;n++)
        kf[n] = *(const bf16x8*)&sK[((n<<4)+r)*64 + ((((kk<<2)+g) ^ (r&7))<<3)];
      #pragma unroll
      for (int m=0;m<2;m++)
        #pragma unroll
        for (int n=0;n<8;n++)
          s[m][n] = __builtin_amdgcn_mfma_f32_16x16x32_bf16(qf[m][kk], kf[n], s[m][n], 0,0,0);
    }
    __builtin_amdgcn_s_setprio(0);
    #pragma unroll
    for (int m=0;m<2;m++)
      #pragma unroll
      for (int n=0;n<8;n++)
        #pragma unroll
        for (int q=0;q<4;q++)
          s[m][n][q] *= SC;

    if (kt == qt) {
      #pragma unroll
      for (int m=0;m<2;m++)
        #pragma unroll
        for (int n=0;n<8;n++) {
          const int tg = (n<<4) + r;
          #pragma unroll
          for (int q=0;q<4;q++) {
            const int qg = w*32 + (m<<4) + (g<<2) + q;
            if (tg > qg) s[m][n][q] = -1e30f;
          }
        }
    }

    #pragma unroll
    for (int m=0;m<2;m++) {
      float f[4], rs[4];
      #pragma unroll
      for (int q=0;q<4;q++) {
        float v = s[m][0][q];
        #pragma unroll
        for (int n=1;n<8;n++) v = fmaxf(v, s[m][n][q]);
        v = fmaxf(v, __shfl_xor(v, 1));
        v = fmaxf(v, __shfl_xor(v, 2));
        v = fmaxf(v, __shfl_xor(v, 4));
        v = fmaxf(v, __shfl_xor(v, 8));
        const float mn = fmaxf(m_run[m][q], v);
        f[q] = exp2f(m_run[m][q] - mn);
        m_run[m][q] = mn;
        rs[q] = 0.f;
      }
      #pragma unroll
      for (int n=0;n<8;n++) {
        #pragma unroll
        for (int q=0;q<4;q++) {
          const float p = exp2f(s[m][n][q] - m_run[m][q]);
          rs[q] += p;
          const int prow = (m<<4) + (g<<2) + q;
          const int pch = (n<<1) + (r>>3);
          sPw[(swzP(prow, pch)<<3) + (r&7)] = f2bf(p);
        }
      }
      #pragma unroll
      for (int q=0;q<4;q++) {
        rs[q] += __shfl_xor(rs[q], 1);
        rs[q] += __shfl_xor(rs[q], 2);
        rs[q] += __shfl_xor(rs[q], 4);
        rs[q] += __shfl_xor(rs[q], 8);
        l_run[m][q] = l_run[m][q]*f[q] + rs[q];
      }
      #pragma unroll
      for (int n=0;n<4;n++)
        #pragma unroll
        for (int q=0;q<4;q++)
          aco[m][n][q] *= f[q];
    }

    __builtin_amdgcn_s_waitcnt(0);
    __builtin_amdgcn_sched_barrier(0);

    __builtin_amdgcn_s_setprio(1);
    #pragma unroll
    for (int kk=0;kk<4;kk++) {
      bf16x8 pf[2], vf[4];
      #pragma unroll
      for (int m=0;m<2;m++)
        pf[m] = *(const bf16x8*)&sPw[swzP((m<<4)+r, (kk<<2)+g)<<3];
      #pragma unroll
      for (int n=0;n<4;n++)
        vf[n] = *(const bf16x8*)&sV[(((n<<4)+r)*17 + (kk<<2) + g)<<3];
      #pragma unroll
      for (int m=0;m<2;m++)
        #pragma unroll
        for (int n=0;n<4;n++)
          aco[m][n] = __builtin_amdgcn_mfma_f32_16x16x32_bf16(pf[m], vf[n], aco[m][n], 0,0,0);
    }
    __builtin_amdgcn_s_setprio(0);
  }

  if (nsplit == 1) {
    #pragma unroll
    for (int m=0;m<2;m++)
      #pragma unroll
      for (int n=0;n<4;n++) {
        const int col = hd*HD + (n<<4) + r;
        #pragma unroll
        for (int q=0;q<4;q++) {
          const int qg = qt*128 + w*32 + (m<<4) + (g<<2) + q;
          o[(size_t)(b*SLEN + qg) * E + col] = f2bf(aco[m][n][q] / l_run[m][q]);
        }
      }
  } else {
    const size_t pb = (((size_t)z*32 + bn)*4 + (qt - 4)) * 128;
    float* op = opart + pb * 64;
    #pragma unroll
    for (int m=0;m<2;m++)
      #pragma unroll
      for (int n=0;n<4;n++) {
        #pragma unroll
        for (int q=0;q<4;q++) {
          const int row = w*32 + (m<<4) + (g<<2) + q;
          op[(size_t)row * 64 + (n<<4) + r] = aco[m][n][q];
        }
      }
    if (r == 0) {
      #pragma unroll
      for (int m=0;m<2;m++)
        #pragma unroll
        for (int q=0;q<4;q++) {
          const int row = w*32 + (m<<4) + (g<<2) + q;
          mpart[pb + row] = m_run[m][q];
          lpart[pb + row] = l_run[m][q];
        }
    }
  }
}

// ---------------- combine split-attention partials (qt>=4) ------------------
__global__ __launch_bounds__(256)
void attn_combine(const float* __restrict__ opart, const float* __restrict__ mpart,
                  const float* __restrict__ lpart, u16* __restrict__ o)
{
  const int qi = blockIdx.x;        // 0..3 -> qt 4..7
  const int bn = blockIdx.y;
  const int b  = bn >> 4;
  const int hd = bn & 15;
  const int t = threadIdx.x;
  const int row = t >> 1;
  const int c0  = (t & 1) << 5;

  const size_t p0 = ((size_t)bn*4 + qi) * 128 + row;
  const size_t p1 = ((size_t)(32 + bn)*4 + qi) * 128 + row;
  const float m0 = mpart[p0], m1 = mpart[p1];
  const float l0 = lpart[p0], l1 = lpart[p1];
  const float mm = fmaxf(m0, m1);
  const float e0 = exp2f(m0 - mm), e1 = exp2f(m1 - mm);
  const float inv = 1.f / (l0*e0 + l1*e1);

  const float4* q0 = (const float4*)(opart + p0*64 + c0);
  const float4* q1 = (const float4*)(opart + p1*64 + c0);
  u16* ob = o + (size_t)(b*SLEN + (qi+4)*128 + row) * E + hd*HD + c0;
  #pragma unroll
  for (int i=0;i<8;i++) {
    const float4 a = q0[i];
    const float4 c = q1[i];
    float4 v;
    v.x = (a.x*e0 + c.x*e1) * inv;
    v.y = (a.y*e0 + c.y*e1) * inv;
    v.z = (a.z*e0 + c.z*e1) * inv;
    v.w = (a.w*e0 + c.w*e1) * inv;
    uint2 pk; pk.x = pk2(v.x, v.y); pk.y = pk2(v.z, v.w);
    ((uint2*)ob)[i] = pk;
  }
}

// -------- LayerNorm over (a [+ a2] [+ res]), dual f32/bf16 outputs ----------
__global__ __launch_bounds__(256)
void ln_row(const float* __restrict__ a, const float* __restrict__ a2,
            const float* __restrict__ res,
            const float* __restrict__ lw, const float* __restrict__ lb,
            float* __restrict__ out32, u16* __restrict__ outb)
{
  __shared__ float red[8];
  const int row = blockIdx.x;
  const int i = threadIdx.x;
  float4 v = ((const float4*)(a + ((size_t)row << 10)))[i];
  if (a2 != nullptr) {
    const float4 rv = ((const float4*)(a2 + ((size_t)row << 10)))[i];
    v.x += rv.x; v.y += rv.y; v.z += rv.z; v.w += rv.w;
  }
  if (res != nullptr) {
    const float4 rv = ((const float4*)(res + ((size_t)row << 10)))[i];
    v.x += rv.x; v.y += rv.y; v.z += rv.z; v.w += rv.w;
  }
  float s1 = v.x + v.y + v.z + v.w;
  float s2 = v.x*v.x + v.y*v.y + v.z*v.z + v.w*v.w;
  #pragma unroll
  for (int off=1; off<64; off<<=1) { s1 += __shfl_xor(s1, off); s2 += __shfl_xor(s2, off); }
  if ((i & 63) == 0) { red[(i>>6)*2] = s1; red[(i>>6)*2+1] = s2; }
  __syncthreads();
  s1 = red[0] + red[2] + red[4] + red[6];
  s2 = red[1] + red[3] + red[5] + red[7];
  const float mean = s1 * (1.f/1024.f);
  const float var  = s2 * (1.f/1024.f) - mean*mean;
  const float rstd = rsqrtf(var + 1e-5f);
  const float4 wv = ((const float4*)lw)[i];
  const float4 bv = ((const float4*)lb)[i];
  float4 ov;
  ov.x = (v.x - mean)*rstd*wv.x + bv.x;
  ov.y = (v.y - mean)*rstd*wv.y + bv.y;
  ov.z = (v.z - mean)*rstd*wv.z + bv.z;
  ov.w = (v.w - mean)*rstd*wv.w + bv.w;
  if (out32) ((float4*)(out32 + ((size_t)row << 10)))[i] = ov;
  if (outb) {
    uint2 pk; pk.x = pk2(ov.x, ov.y); pk.y = pk2(ov.z, ov.w);
    ((uint2*)(outb + ((size_t)row << 10)))[i] = pk;
  }
}

// ---------------- Embedding + decoder LN, dual outputs ----------------------
__global__ __launch_bounds__(256)
void embed_ln(const int* __restrict__ x, const float* __restrict__ tok,
              const float* __restrict__ pos, const float* __restrict__ lw,
              const float* __restrict__ lb, float* __restrict__ h32,
              u16* __restrict__ hb)
{
  __shared__ float red[8];
  const int row = blockIdx.x;
  const int s = row & (SLEN-1);
  const int i = threadIdx.x;
  const int id = x[row];
  const float4 tv = ((const float4*)(tok + ((size_t)id << 10)))[i];
  const float4 pv = ((const float4*)(pos + ((size_t)s << 10)))[i];
  float4 v;
  v.x = tv.x + pv.x; v.y = tv.y + pv.y; v.z = tv.z + pv.z; v.w = tv.w + pv.w;
  float s1 = v.x + v.y + v.z + v.w;
  float s2 = v.x*v.x + v.y*v.y + v.z*v.z + v.w*v.w;
  #pragma unroll
  for (int off=1; off<64; off<<=1) { s1 += __shfl_xor(s1, off); s2 += __shfl_xor(s2, off); }
  if ((i & 63) == 0) { red[(i>>6)*2] = s1; red[(i>>6)*2+1] = s2; }
  __syncthreads();
  s1 = red[0] + red[2] + red[4] + red[6];
  s2 = red[1] + red[3] + red[5] + red[7];
  const float mean = s1 * (1.f/1024.f);
  const float var  = s2 * (1.f/1024.f) - mean*mean;
  const float rstd = rsqrtf(var + 1e-5f);
  const float4 wv = ((const float4*)lw)[i];
  const float4 bv = ((const float4*)lb)[i];
  float4 ov;
  ov.x = (v.x - mean)*rstd*wv.x + bv.x;
  ov.y = (v.y - mean)*rstd*wv.y + bv.y;
  ov.z = (v.z - mean)*rstd*wv.z + bv.z;
  ov.w = (v.w - mean)*rstd*wv.w + bv.w;
  ((float4*)(h32 + ((size_t)row << 10)))[i] = ov;
  uint2 pk; pk.x = pk2(ov.x, ov.y); pk.y = pk2(ov.z, ov.w);
  ((uint2*)(hb + ((size_t)row << 10)))[i] = pk;
}

extern "C" void kernel_launch(void* const* d_in, const int* in_sizes, int n_in,
                              void* d_out, int out_size, void* d_ws, size_t ws_size,
                              hipStream_t stream) {
  const int*   x    = (const int*)  d_in[0];
  const float* tok  = (const float*)d_in[1];
  const float* pos  = (const float*)d_in[2];
  const float* decw = (const float*)d_in[3];
  const float* decb = (const float*)d_in[4];
  const float* qkvw = (const float*)d_in[5];
  const float* qkvb = (const float*)d_in[6];
  const float* apw  = (const float*)d_in[7];
  const float* apb  = (const float*)d_in[8];
  const float* l1w  = (const float*)d_in[9];
  const float* l1b  = (const float*)d_in[10];
  const float* fcw  = (const float*)d_in[11];
  const float* fcb  = (const float*)d_in[12];
  const float* mpw  = (const float*)d_in[13];
  const float* mpb  = (const float*)d_in[14];
  const float* l2w  = (const float*)d_in[15];
  const float* l2b  = (const float*)d_in[16];
  const float* finw = (const float*)d_in[17];
  const float* finb = (const float*)d_in[18];
  float* out = (float*)d_out;

  // workspace (~280 MB of ~800 MB)
  char* p = (char*)d_ws;
  float* h32   = (float*)p;                p += (size_t)2048*1024*4;     // 8 MB
  float* part  = (float*)p;                p += (size_t)2*2048*1024*4;   // 16 MB
  float* opart = (float*)p;                p += (size_t)2*32*4*128*64*4; // 8 MB
  float* mpart = (float*)p;                p += (size_t)2*32*4*128*4;    // 128 KB
  float* lpart = (float*)p;                p += (size_t)2*32*4*128*4;    // 128 KB
  u16*   hb    = (u16*)p;                  p += (size_t)2048*1024*2;     // 4 MB
  u16*   qkvB  = (u16*)p;                  p += (size_t)2048*3072*2;     // 12 MB
  u16*   ab    = (u16*)p;                  p += (size_t)2048*1024*2;     // 4 MB
  u16*   fb    = (u16*)p;                  p += (size_t)2048*4096*2;     // 16 MB
  u16*   wq    = (u16*)p;                  p += (size_t)8*3072*1024*2;   // 48 MB
  u16*   wap   = (u16*)p;                  p += (size_t)8*1024*1024*2;   // 16 MB
  u16*   wfc   = (u16*)p;                  p += (size_t)8*4096*1024*2;   // 64 MB
  u16*   wmp   = (u16*)p;                  p += (size_t)8*4096*1024*2;   // 64 MB
  float* part1 = part + (size_t)2048*1024;

  f2b_conv4<<<4096, 256, 0, stream>>>(qkvw, wq,  8*3072*1024/8,
                                      apw,  wap, 8*1024*1024/8,
                                      fcw,  wfc, 8*4096*1024/8,
                                      mpw,  wmp, 8*4096*1024/8);

  embed_ln<<<2048, 256, 0, stream>>>(x, tok, pos, decw, decb, h32, hb);

  for (int l = 0; l < 8; ++l) {
    const u16* lwq  = wq  + (size_t)l*3072*1024;
    const u16* lwap = wap + (size_t)l*1024*1024;
    const u16* lwfc = wfc + (size_t)l*4096*1024;
    const u16* lwmp = wmp + (size_t)l*4096*1024;

    gemm_lds<128,1,0,1><<<dim3(24,16),   256, 0, stream>>>(hb, lwq,  qkvb + (size_t)l*3072, qkvB, 2048, 3072, 1024);
    attn_fwd<<<dim3(12,32), 256, 0, stream>>>(qkvB, ab, opart, mpart, lpart);
    attn_combine<<<dim3(4,32), 256, 0, stream>>>(opart, mpart, lpart, ab);
    gemm_lds<128,0,0,2><<<dim3(8,16,2),  256, 0, stream>>>(ab, lwap, apb + (size_t)l*1024, part, 2048, 1024, 1024);
    ln_row<<<2048, 256, 0, stream>>>(part, part1, h32, l1w + (size_t)l*1024, l1b + (size_t)l*1024, h32, hb);
    gemm_lds<128,1,1,1><<<dim3(32,16),   256, 0, stream>>>(hb, lwfc, fcb + (size_t)l*4096, fb, 2048, 4096, 1024);
    gemm_lds<128,0,0,2><<<dim3(8,16,2),  256, 0, stream>>>(fb, lwmp, mpb + (size_t)l*1024, part, 2048, 1024, 4096);
    ln_row<<<2048, 256, 0, stream>>>(part, part1, h32, l2w + (size_t)l*1024, l2b + (size_t)l*1024, h32, hb);
  }

  ln_row<<<2048, 256, 0, stream>>>(h32, nullptr, nullptr, finw, finb, out, nullptr);
}

// Round 7
// 1472.798 us; speedup vs baseline: 2.0018x; 1.0176x over previous
//
#include <hip/hip_runtime.h>
#include <hip/hip_bf16.h>

#define E 1024
#define SLEN 1024
#define QKV3 3072
#define HD 64

typedef unsigned short u16;
typedef unsigned int   u32;
typedef __bf16 bf16x8 __attribute__((ext_vector_type(8)));
typedef float  f32x4  __attribute__((ext_vector_type(4)));
typedef float  fv4    __attribute__((ext_vector_type(4)));
typedef u32    uv2    __attribute__((ext_vector_type(2)));

__device__ __forceinline__ u16 f2bf(float f) {
  __hip_bfloat16 h = __float2bfloat16(f);
  return __builtin_bit_cast(u16, h);
}
__device__ __forceinline__ u32 pk2(float a, float b) {
  return (u32)f2bf(a) | ((u32)f2bf(b) << 16);
}
__device__ __forceinline__ uint4 pack8(const float4& x, const float4& y) {
  return make_uint4(pk2(x.x,x.y), pk2(x.z,x.w), pk2(y.x,y.y), pk2(y.z,y.w));
}

// async global->LDS, 16B per lane; LDS dest = wave-uniform base + lane*16
__device__ __forceinline__ void gload16(const u16* g, u16* l) {
  __builtin_amdgcn_global_load_lds(
      (const __attribute__((address_space(1))) void*)g,
      (__attribute__((address_space(3))) void*)l, 16, 0, 0);
}

// P-buffer granule swizzle (attention, verified round 1)
__device__ __forceinline__ int swzP(int row, int ch) { return (row<<4) + (ch ^ (row & 7)); }

// ------------- f32 -> bf16 streaming convert (contiguous, nontemporal) ------
// thread i: one float4 (16B lane-contiguous read) -> one uint2 (8B write)
__global__ __launch_bounds__(256)
void f2b(const float* __restrict__ src, u16* __restrict__ dst, int n4)
{
  const int stride = gridDim.x * 256;
  const fv4* s4 = (const fv4*)src;
  uv2* d2 = (uv2*)dst;
  for (int i = blockIdx.x * 256 + threadIdx.x; i < n4; i += stride) {
    const fv4 v = __builtin_nontemporal_load(s4 + i);
    uv2 o; o.x = pk2(v.x, v.y); o.y = pk2(v.z, v.w);
    __builtin_nontemporal_store(o, d2 + i);
  }
}

// ---------------- GEMM: C = A[M][K] @ W[N][K]^T + bias ----------------------
// bf16 A,W via global_load_lds; BM=128, BK=32, 256 threads (2x2 waves).
// T3/T4: 3-buffer ring, depth-2 prefetch, counted vmcnt (never 0 mid-loop),
// raw s_barrier (no implicit drain). SK>1: split-K partial planes.
template<int BN, int OUTBF, int GELU, int SK>
__global__ __launch_bounds__(256)
void gemm_lds(const u16* __restrict__ A, const u16* __restrict__ W,
              const float* __restrict__ bias, void* __restrict__ Cv,
              int M, int N, int K)
{
  static_assert(!(GELU && SK > 1), "gelu needs full sum");
  static_assert(!(OUTBF && SK > 1), "partials are f32");
  constexpr int BM = 128;
  __shared__ __align__(16) u16 sA[3][BM*32];
  __shared__ __align__(16) u16 sB[3][BN*32];

  const int t = threadIdx.x;
  const int lane = t & 63;
  const int w = t >> 6;
  const int r = lane & 15;
  const int g = lane >> 4;
  const int wr = (w >> 1) * 64;
  const int wc = (w & 1) * (BN/2);

  const int row0 = blockIdx.y * BM;
  const int col0 = blockIdx.x * BN;
  const int k0   = (SK > 1) ? (int)blockIdx.z * (K / SK) : 0;

  constexpr int ACH = BM/16;
  constexpr int NCH = ACH + BN/16;
  constexpr int CPW = NCH/4;

  const int lrow = lane >> 2;
  const int lcol = (lane & 3) << 3;

  f32x4 acc[4][BN/32];
  #pragma unroll
  for (int i=0;i<4;i++)
    #pragma unroll
    for (int j=0;j<BN/32;j++)
      acc[i][j] = f32x4{0.f,0.f,0.f,0.f};

  const int nk = (K / SK) >> 5;

  auto stage = [&](int kt, int buf) {
    #pragma unroll
    for (int i = 0; i < CPW; ++i) {
      const int c = w*CPW + i;
      if (c < ACH) {
        const u16* gp = A + (size_t)(row0 + c*16 + lrow) * K + k0 + (kt<<5) + lcol;
        gload16(gp, &sA[buf][c*512]);
      } else {
        const int cb = c - ACH;
        const u16* gp = W + (size_t)(col0 + cb*16 + lrow) * K + k0 + (kt<<5) + lcol;
        gload16(gp, &sB[buf][cb*512]);
      }
    }
  };

  stage(0, 0);
  if (nk > 1) stage(1, 1);

  int cur = 0;
  for (int kt = 0; kt < nk; ++kt) {
    if (kt + 1 < nk) asm volatile("s_waitcnt vmcnt(4)" ::: "memory");
    else             asm volatile("s_waitcnt vmcnt(0)" ::: "memory");
    __builtin_amdgcn_s_barrier();

    if (kt + 2 < nk) stage(kt + 2, (cur + 2 >= 3) ? cur - 1 : cur + 2);

    bf16x8 af[4], bfr[BN/32];
    #pragma unroll
    for (int m=0;m<4;m++)
      af[m] = *(const bf16x8*)&sA[cur][(wr + (m<<4) + r)*32 + (g<<3)];
    #pragma unroll
    for (int n=0;n<BN/32;n++)
      bfr[n] = *(const bf16x8*)&sB[cur][(wc + (n<<4) + r)*32 + (g<<3)];
    #pragma unroll
    for (int m=0;m<4;m++)
      #pragma unroll
      for (int n=0;n<BN/32;n++)
        acc[m][n] = __builtin_amdgcn_mfma_f32_16x16x32_bf16(af[m], bfr[n], acc[m][n], 0, 0, 0);

    cur = (cur + 1 >= 3) ? 0 : cur + 1;
  }

  float* C32 = (float*)Cv + ((SK > 1) ? (size_t)blockIdx.z * M * N : 0);

  #pragma unroll
  for (int n=0;n<BN/32;n++) {
    const int col = col0 + wc + (n<<4) + r;
    const float bv = (SK == 1 || blockIdx.z == 0) ? bias[col] : 0.f;
    #pragma unroll
    for (int m=0;m<4;m++) {
      const int rowb = row0 + wr + (m<<4) + (g<<2);
      #pragma unroll
      for (int q=0;q<4;q++) {
        float v = acc[m][n][q] + bv;
        if (GELU) v = 0.5f * v * (1.f + erff(v * 0.70710678118f));
        if (OUTBF) ((u16*)Cv)[(size_t)(rowb + q) * N + col] = f2bf(v);
        else       C32[(size_t)(rowb + q) * N + col] = v;
      }
    }
  }
}

// ---------------- Flash attention, causal-balanced key-split ----------------
// grid (12 jobs, 32 b*head). Jobs: qt>=4 split into 2 key-range halves
// (partials to ws); qt<4 single block writing bf16 output directly.
__global__ __launch_bounds__(256)
void attn_fwd(const u16* __restrict__ qkv, u16* __restrict__ o,
              float* __restrict__ opart, float* __restrict__ mpart,
              float* __restrict__ lpart)
{
  __shared__ __align__(16) u16 sK[128*64];
  __shared__ __align__(16) u16 sV[64*136];
  __shared__ __align__(16) u16 sP[4*32*128];

  const int j  = blockIdx.x;
  int qt, z, nsplit;
  if (j < 8) { qt = 7 - (j >> 1); z = j & 1; nsplit = 2; }
  else       { qt = 11 - j;       z = 0;     nsplit = 1; }
  const int half = (qt + 1) >> 1;
  const int kt0 = (nsplit == 2 && z == 1) ? half : 0;
  const int kt1 = (nsplit == 2 && z == 0) ? half : qt + 1;

  const int bn = blockIdx.y;
  const int b  = bn >> 4;
  const int hd = bn & 15;

  const int t = threadIdx.x;
  const int lane = t & 63;
  const int w = t >> 6;
  const int r = lane & 15;
  const int g = lane >> 4;

  const float SC = 0.125f * 1.44269504089f;

  bf16x8 qf[2][2];
  #pragma unroll
  for (int m=0;m<2;m++)
    #pragma unroll
    for (int kk=0;kk<2;kk++)
      qf[m][kk] = *(const bf16x8*)(qkv + (size_t)(b*SLEN + qt*128 + w*32 + (m<<4) + r) * QKV3
                                   + hd*HD + (kk<<5) + (g<<3));

  float m_run[2][4], l_run[2][4];
  f32x4 aco[2][4];
  #pragma unroll
  for (int m=0;m<2;m++) {
    #pragma unroll
    for (int q=0;q<4;q++) { m_run[m][q] = -1e30f; l_run[m][q] = 0.f; }
    #pragma unroll
    for (int n=0;n<4;n++) aco[m][n] = f32x4{0.f,0.f,0.f,0.f};
  }

  u16* sPw = sP + (w << 12);

  for (int kt = kt0; kt < kt1; ++kt) {
    __syncthreads();
    {
      const int rl = lane >> 3;
      const int hc = (lane & 7) ^ rl;
      #pragma unroll
      for (int i=0;i<4;i++) {
        const int c = w*4 + i;
        const u16* gp = qkv + (size_t)(b*SLEN + kt*128 + c*8 + rl) * QKV3
                      + E + hd*HD + (hc<<3);
        gload16(gp, &sK[c*512]);
      }
    }
    {
      const int vh = t & 63;
      const int tb = (t >> 6) << 5;
      const u16* vp = qkv + (size_t)(b*SLEN + kt*128 + tb) * QKV3 + 2*E + hd*HD + vh;
      #pragma unroll
      for (int i=0;i<32;i+=2) {
        const u32 v0 = vp[(size_t)i * QKV3];
        const u32 v1 = vp[(size_t)(i+1) * QKV3];
        const int tt = tb + i;
        const int gran = vh*17 + (tt >> 3);
        *(u32*)&sV[(gran<<3) + (tt & 7)] = v0 | (v1 << 16);
      }
    }
    __syncthreads();

    f32x4 s[2][8];
    #pragma unroll
    for (int m=0;m<2;m++)
      #pragma unroll
      for (int n=0;n<8;n++)
        s[m][n] = f32x4{0.f,0.f,0.f,0.f};
    __builtin_amdgcn_s_setprio(1);
    #pragma unroll
    for (int kk=0;kk<2;kk++) {
      bf16x8 kf[8];
      #pragma unroll
      for (int n=0;n<8;n++)
        kf[n] = *(const bf16x8*)&sK[((n<<4)+r)*64 + ((((kk<<2)+g) ^ (r&7))<<3)];
      #pragma unroll
      for (int m=0;m<2;m++)
        #pragma unroll
        for (int n=0;n<8;n++)
          s[m][n] = __builtin_amdgcn_mfma_f32_16x16x32_bf16(qf[m][kk], kf[n], s[m][n], 0,0,0);
    }
    __builtin_amdgcn_s_setprio(0);
    #pragma unroll
    for (int m=0;m<2;m++)
      #pragma unroll
      for (int n=0;n<8;n++)
        #pragma unroll
        for (int q=0;q<4;q++)
          s[m][n][q] *= SC;

    if (kt == qt) {
      #pragma unroll
      for (int m=0;m<2;m++)
        #pragma unroll
        for (int n=0;n<8;n++) {
          const int tg = (n<<4) + r;
          #pragma unroll
          for (int q=0;q<4;q++) {
            const int qg = w*32 + (m<<4) + (g<<2) + q;
            if (tg > qg) s[m][n][q] = -1e30f;
          }
        }
    }

    #pragma unroll
    for (int m=0;m<2;m++) {
      float f[4], rs[4];
      #pragma unroll
      for (int q=0;q<4;q++) {
        float v = s[m][0][q];
        #pragma unroll
        for (int n=1;n<8;n++) v = fmaxf(v, s[m][n][q]);
        v = fmaxf(v, __shfl_xor(v, 1));
        v = fmaxf(v, __shfl_xor(v, 2));
        v = fmaxf(v, __shfl_xor(v, 4));
        v = fmaxf(v, __shfl_xor(v, 8));
        const float mn = fmaxf(m_run[m][q], v);
        f[q] = exp2f(m_run[m][q] - mn);
        m_run[m][q] = mn;
        rs[q] = 0.f;
      }
      #pragma unroll
      for (int n=0;n<8;n++) {
        #pragma unroll
        for (int q=0;q<4;q++) {
          const float p = exp2f(s[m][n][q] - m_run[m][q]);
          rs[q] += p;
          const int prow = (m<<4) + (g<<2) + q;
          const int pch = (n<<1) + (r>>3);
          sPw[(swzP(prow, pch)<<3) + (r&7)] = f2bf(p);
        }
      }
      #pragma unroll
      for (int q=0;q<4;q++) {
        rs[q] += __shfl_xor(rs[q], 1);
        rs[q] += __shfl_xor(rs[q], 2);
        rs[q] += __shfl_xor(rs[q], 4);
        rs[q] += __shfl_xor(rs[q], 8);
        l_run[m][q] = l_run[m][q]*f[q] + rs[q];
      }
      #pragma unroll
      for (int n=0;n<4;n++)
        #pragma unroll
        for (int q=0;q<4;q++)
          aco[m][n][q] *= f[q];
    }

    __builtin_amdgcn_s_waitcnt(0);
    __builtin_amdgcn_sched_barrier(0);

    __builtin_amdgcn_s_setprio(1);
    #pragma unroll
    for (int kk=0;kk<4;kk++) {
      bf16x8 pf[2], vf[4];
      #pragma unroll
      for (int m=0;m<2;m++)
        pf[m] = *(const bf16x8*)&sPw[swzP((m<<4)+r, (kk<<2)+g)<<3];
      #pragma unroll
      for (int n=0;n<4;n++)
        vf[n] = *(const bf16x8*)&sV[(((n<<4)+r)*17 + (kk<<2) + g)<<3];
      #pragma unroll
      for (int m=0;m<2;m++)
        #pragma unroll
        for (int n=0;n<4;n++)
          aco[m][n] = __builtin_amdgcn_mfma_f32_16x16x32_bf16(pf[m], vf[n], aco[m][n], 0,0,0);
    }
    __builtin_amdgcn_s_setprio(0);
  }

  if (nsplit == 1) {
    #pragma unroll
    for (int m=0;m<2;m++)
      #pragma unroll
      for (int n=0;n<4;n++) {
        const int col = hd*HD + (n<<4) + r;
        #pragma unroll
        for (int q=0;q<4;q++) {
          const int qg = qt*128 + w*32 + (m<<4) + (g<<2) + q;
          o[(size_t)(b*SLEN + qg) * E + col] = f2bf(aco[m][n][q] / l_run[m][q]);
        }
      }
  } else {
    const size_t pb = (((size_t)z*32 + bn)*4 + (qt - 4)) * 128;
    float* op = opart + pb * 64;
    #pragma unroll
    for (int m=0;m<2;m++)
      #pragma unroll
      for (int n=0;n<4;n++) {
        #pragma unroll
        for (int q=0;q<4;q++) {
          const int row = w*32 + (m<<4) + (g<<2) + q;
          op[(size_t)row * 64 + (n<<4) + r] = aco[m][n][q];
        }
      }
    if (r == 0) {
      #pragma unroll
      for (int m=0;m<2;m++)
        #pragma unroll
        for (int q=0;q<4;q++) {
          const int row = w*32 + (m<<4) + (g<<2) + q;
          mpart[pb + row] = m_run[m][q];
          lpart[pb + row] = l_run[m][q];
        }
    }
  }
}

// ---------------- combine split-attention partials (qt>=4) ------------------
__global__ __launch_bounds__(256)
void attn_combine(const float* __restrict__ opart, const float* __restrict__ mpart,
                  const float* __restrict__ lpart, u16* __restrict__ o)
{
  const int qi = blockIdx.x;        // 0..3 -> qt 4..7
  const int bn = blockIdx.y;
  const int b  = bn >> 4;
  const int hd = bn & 15;
  const int t = threadIdx.x;
  const int row = t >> 1;
  const int c0  = (t & 1) << 5;

  const size_t p0 = ((size_t)bn*4 + qi) * 128 + row;
  const size_t p1 = ((size_t)(32 + bn)*4 + qi) * 128 + row;
  const float m0 = mpart[p0], m1 = mpart[p1];
  const float l0 = lpart[p0], l1 = lpart[p1];
  const float mm = fmaxf(m0, m1);
  const float e0 = exp2f(m0 - mm), e1 = exp2f(m1 - mm);
  const float inv = 1.f / (l0*e0 + l1*e1);

  const float4* q0 = (const float4*)(opart + p0*64 + c0);
  const float4* q1 = (const float4*)(opart + p1*64 + c0);
  u16* ob = o + (size_t)(b*SLEN + (qi+4)*128 + row) * E + hd*HD + c0;
  #pragma unroll
  for (int i=0;i<8;i++) {
    const float4 a = q0[i];
    const float4 c = q1[i];
    float4 v;
    v.x = (a.x*e0 + c.x*e1) * inv;
    v.y = (a.y*e0 + c.y*e1) * inv;
    v.z = (a.z*e0 + c.z*e1) * inv;
    v.w = (a.w*e0 + c.w*e1) * inv;
    uint2 pk; pk.x = pk2(v.x, v.y); pk.y = pk2(v.z, v.w);
    ((uint2*)ob)[i] = pk;
  }
}

// -------- LayerNorm over (a [+ a2] [+ res]), dual f32/bf16 outputs ----------
__global__ __launch_bounds__(256)
void ln_row(const float* __restrict__ a, const float* __restrict__ a2,
            const float* __restrict__ res,
            const float* __restrict__ lw, const float* __restrict__ lb,
            float* __restrict__ out32, u16* __restrict__ outb)
{
  __shared__ float red[8];
  const int row = blockIdx.x;
  const int i = threadIdx.x;
  float4 v = ((const float4*)(a + ((size_t)row << 10)))[i];
  if (a2 != nullptr) {
    const float4 rv = ((const float4*)(a2 + ((size_t)row << 10)))[i];
    v.x += rv.x; v.y += rv.y; v.z += rv.z; v.w += rv.w;
  }
  if (res != nullptr) {
    const float4 rv = ((const float4*)(res + ((size_t)row << 10)))[i];
    v.x += rv.x; v.y += rv.y; v.z += rv.z; v.w += rv.w;
  }
  float s1 = v.x + v.y + v.z + v.w;
  float s2 = v.x*v.x + v.y*v.y + v.z*v.z + v.w*v.w;
  #pragma unroll
  for (int off=1; off<64; off<<=1) { s1 += __shfl_xor(s1, off); s2 += __shfl_xor(s2, off); }
  if ((i & 63) == 0) { red[(i>>6)*2] = s1; red[(i>>6)*2+1] = s2; }
  __syncthreads();
  s1 = red[0] + red[2] + red[4] + red[6];
  s2 = red[1] + red[3] + red[5] + red[7];
  const float mean = s1 * (1.f/1024.f);
  const float var  = s2 * (1.f/1024.f) - mean*mean;
  const float rstd = rsqrtf(var + 1e-5f);
  const float4 wv = ((const float4*)lw)[i];
  const float4 bv = ((const float4*)lb)[i];
  float4 ov;
  ov.x = (v.x - mean)*rstd*wv.x + bv.x;
  ov.y = (v.y - mean)*rstd*wv.y + bv.y;
  ov.z = (v.z - mean)*rstd*wv.z + bv.z;
  ov.w = (v.w - mean)*rstd*wv.w + bv.w;
  if (out32) ((float4*)(out32 + ((size_t)row << 10)))[i] = ov;
  if (outb) {
    uint2 pk; pk.x = pk2(ov.x, ov.y); pk.y = pk2(ov.z, ov.w);
    ((uint2*)(outb + ((size_t)row << 10)))[i] = pk;
  }
}

// ---------------- Embedding + decoder LN, dual outputs ----------------------
__global__ __launch_bounds__(256)
void embed_ln(const int* __restrict__ x, const float* __restrict__ tok,
              const float* __restrict__ pos, const float* __restrict__ lw,
              const float* __restrict__ lb, float* __restrict__ h32,
              u16* __restrict__ hb)
{
  __shared__ float red[8];
  const int row = blockIdx.x;
  const int s = row & (SLEN-1);
  const int i = threadIdx.x;
  const int id = x[row];
  const float4 tv = ((const float4*)(tok + ((size_t)id << 10)))[i];
  const float4 pv = ((const float4*)(pos + ((size_t)s << 10)))[i];
  float4 v;
  v.x = tv.x + pv.x; v.y = tv.y + pv.y; v.z = tv.z + pv.z; v.w = tv.w + pv.w;
  float s1 = v.x + v.y + v.z + v.w;
  float s2 = v.x*v.x + v.y*v.y + v.z*v.z + v.w*v.w;
  #pragma unroll
  for (int off=1; off<64; off<<=1) { s1 += __shfl_xor(s1, off); s2 += __shfl_xor(s2, off); }
  if ((i & 63) == 0) { red[(i>>6)*2] = s1; red[(i>>6)*2+1] = s2; }
  __syncthreads();
  s1 = red[0] + red[2] + red[4] + red[6];
  s2 = red[1] + red[3] + red[5] + red[7];
  const float mean = s1 * (1.f/1024.f);
  const float var  = s2 * (1.f/1024.f) - mean*mean;
  const float rstd = rsqrtf(var + 1e-5f);
  const float4 wv = ((const float4*)lw)[i];
  const float4 bv = ((const float4*)lb)[i];
  float4 ov;
  ov.x = (v.x - mean)*rstd*wv.x + bv.x;
  ov.y = (v.y - mean)*rstd*wv.y + bv.y;
  ov.z = (v.z - mean)*rstd*wv.z + bv.z;
  ov.w = (v.w - mean)*rstd*wv.w + bv.w;
  ((float4*)(h32 + ((size_t)row << 10)))[i] = ov;
  uint2 pk; pk.x = pk2(ov.x, ov.y); pk.y = pk2(ov.z, ov.w);
  ((uint2*)(hb + ((size_t)row << 10)))[i] = pk;
}

extern "C" void kernel_launch(void* const* d_in, const int* in_sizes, int n_in,
                              void* d_out, int out_size, void* d_ws, size_t ws_size,
                              hipStream_t stream) {
  const int*   x    = (const int*)  d_in[0];
  const float* tok  = (const float*)d_in[1];
  const float* pos  = (const float*)d_in[2];
  const float* decw = (const float*)d_in[3];
  const float* decb = (const float*)d_in[4];
  const float* qkvw = (const float*)d_in[5];
  const float* qkvb = (const float*)d_in[6];
  const float* apw  = (const float*)d_in[7];
  const float* apb  = (const float*)d_in[8];
  const float* l1w  = (const float*)d_in[9];
  const float* l1b  = (const float*)d_in[10];
  const float* fcw  = (const float*)d_in[11];
  const float* fcb  = (const float*)d_in[12];
  const float* mpw  = (const float*)d_in[13];
  const float* mpb  = (const float*)d_in[14];
  const float* l2w  = (const float*)d_in[15];
  const float* l2b  = (const float*)d_in[16];
  const float* finw = (const float*)d_in[17];
  const float* finb = (const float*)d_in[18];
  float* out = (float*)d_out;

  // workspace (~280 MB of ~800 MB)
  char* p = (char*)d_ws;
  float* h32   = (float*)p;                p += (size_t)2048*1024*4;     // 8 MB
  float* part  = (float*)p;                p += (size_t)2*2048*1024*4;   // 16 MB
  float* opart = (float*)p;                p += (size_t)2*32*4*128*64*4; // 8 MB
  float* mpart = (float*)p;                p += (size_t)2*32*4*128*4;    // 128 KB
  float* lpart = (float*)p;                p += (size_t)2*32*4*128*4;    // 128 KB
  u16*   hb    = (u16*)p;                  p += (size_t)2048*1024*2;     // 4 MB
  u16*   qkvB  = (u16*)p;                  p += (size_t)2048*3072*2;     // 12 MB
  u16*   ab    = (u16*)p;                  p += (size_t)2048*1024*2;     // 4 MB
  u16*   fb    = (u16*)p;                  p += (size_t)2048*4096*2;     // 16 MB
  u16*   wq    = (u16*)p;                  p += (size_t)8*3072*1024*2;   // 48 MB
  u16*   wap   = (u16*)p;                  p += (size_t)8*1024*1024*2;   // 16 MB
  u16*   wfc   = (u16*)p;                  p += (size_t)8*4096*1024*2;   // 64 MB
  u16*   wmp   = (u16*)p;                  p += (size_t)8*4096*1024*2;   // 64 MB
  float* part1 = part + (size_t)2048*1024;

  // all-layer weight conversion (contiguous streaming, nontemporal)
  f2b<<<2048, 256, 0, stream>>>(qkvw, wq,  8*3072*1024/4);
  f2b<<<1024, 256, 0, stream>>>(apw,  wap, 8*1024*1024/4);
  f2b<<<2048, 256, 0, stream>>>(fcw,  wfc, 8*4096*1024/4);
  f2b<<<2048, 256, 0, stream>>>(mpw,  wmp, 8*4096*1024/4);

  embed_ln<<<2048, 256, 0, stream>>>(x, tok, pos, decw, decb, h32, hb);

  for (int l = 0; l < 8; ++l) {
    const u16* lwq  = wq  + (size_t)l*3072*1024;
    const u16* lwap = wap + (size_t)l*1024*1024;
    const u16* lwfc = wfc + (size_t)l*4096*1024;
    const u16* lwmp = wmp + (size_t)l*4096*1024;

    gemm_lds<128,1,0,1><<<dim3(24,16),   256, 0, stream>>>(hb, lwq,  qkvb + (size_t)l*3072, qkvB, 2048, 3072, 1024);
    attn_fwd<<<dim3(12,32), 256, 0, stream>>>(qkvB, ab, opart, mpart, lpart);
    attn_combine<<<dim3(4,32), 256, 0, stream>>>(opart, mpart, lpart, ab);
    gemm_lds<128,0,0,2><<<dim3(8,16,2),  256, 0, stream>>>(ab, lwap, apb + (size_t)l*1024, part, 2048, 1024, 1024);
    ln_row<<<2048, 256, 0, stream>>>(part, part1, h32, l1w + (size_t)l*1024, l1b + (size_t)l*1024, h32, hb);
    gemm_lds<128,1,1,1><<<dim3(32,16),   256, 0, stream>>>(hb, lwfc, fcb + (size_t)l*4096, fb, 2048, 4096, 1024);
    gemm_lds<128,0,0,2><<<dim3(8,16,2),  256, 0, stream>>>(fb, lwmp, mpb + (size_t)l*1024, part, 2048, 1024, 4096);
    ln_row<<<2048, 256, 0, stream>>>(part, part1, h32, l2w + (size_t)l*1024, l2b + (size_t)l*1024, h32, hb);
  }

  ln_row<<<2048, 256, 0, stream>>>(h32, nullptr, nullptr, finw, finb, out, nullptr);
}

// Round 8
// 1414.145 us; speedup vs baseline: 2.0848x; 1.0415x over previous
//
#include <hip/hip_runtime.h>
#include <hip/hip_bf16.h>

#define E 1024
#define SLEN 1024
#define QKV3 3072
#define HD 64

typedef unsigned short u16;
typedef unsigned int   u32;
typedef __bf16 bf16x8 __attribute__((ext_vector_type(8)));
typedef float  f32x4  __attribute__((ext_vector_type(4)));
typedef float  fv4    __attribute__((ext_vector_type(4)));
typedef u32    uv2    __attribute__((ext_vector_type(2)));

__device__ __forceinline__ u16 f2bf(float f) {
  __hip_bfloat16 h = __float2bfloat16(f);
  return __builtin_bit_cast(u16, h);
}
__device__ __forceinline__ u32 pk2(float a, float b) {
  return (u32)f2bf(a) | ((u32)f2bf(b) << 16);
}
__device__ __forceinline__ uint4 pack8(const float4& x, const float4& y) {
  return make_uint4(pk2(x.x,x.y), pk2(x.z,x.w), pk2(y.x,y.y), pk2(y.z,y.w));
}

// async global->LDS, 16B per lane; LDS dest = wave-uniform base + lane*16
__device__ __forceinline__ void gload16(const u16* g, u16* l) {
  __builtin_amdgcn_global_load_lds(
      (const __attribute__((address_space(1))) void*)g,
      (__attribute__((address_space(3))) void*)l, 16, 0, 0);
}

// P-buffer granule swizzle (attention, verified round 1)
__device__ __forceinline__ int swzP(int row, int ch) { return (row<<4) + (ch ^ (row & 7)); }

// ------------- f32 -> bf16 streaming convert ---------------------------------
// nt LOAD only (src never reused); plain store so bf16 weights stay L2/L3-
// resident for the GEMMs that read them right after.
__global__ __launch_bounds__(256)
void f2b(const float* __restrict__ src, u16* __restrict__ dst, int n4)
{
  const int stride = gridDim.x * 256;
  const fv4* s4 = (const fv4*)src;
  uv2* d2 = (uv2*)dst;
  for (int i = blockIdx.x * 256 + threadIdx.x; i < n4; i += stride) {
    const fv4 v = __builtin_nontemporal_load(s4 + i);
    uv2 o; o.x = pk2(v.x, v.y); o.y = pk2(v.z, v.w);
    d2[i] = o;
  }
}

// ---------------- GEMM: C = A[M][K] @ W[N][K]^T + bias ----------------------
// bf16 A,W via global_load_lds; BM=128, BK=32, 256 threads (2x2 waves).
// T3/T4: 3-buffer ring, depth-2 prefetch, counted vmcnt (never 0 mid-loop),
// raw s_barrier (no implicit drain). SK>1: split-K partial planes.
template<int BN, int OUTBF, int GELU, int SK>
__global__ __launch_bounds__(256)
void gemm_lds(const u16* __restrict__ A, const u16* __restrict__ W,
              const float* __restrict__ bias, void* __restrict__ Cv,
              int M, int N, int K)
{
  static_assert(!(GELU && SK > 1), "gelu needs full sum");
  static_assert(!(OUTBF && SK > 1), "partials are f32");
  constexpr int BM = 128;
  __shared__ __align__(16) u16 sA[3][BM*32];
  __shared__ __align__(16) u16 sB[3][BN*32];

  const int t = threadIdx.x;
  const int lane = t & 63;
  const int w = t >> 6;
  const int r = lane & 15;
  const int g = lane >> 4;
  const int wr = (w >> 1) * 64;
  const int wc = (w & 1) * (BN/2);

  const int row0 = blockIdx.y * BM;
  const int col0 = blockIdx.x * BN;
  const int k0   = (SK > 1) ? (int)blockIdx.z * (K / SK) : 0;

  constexpr int ACH = BM/16;
  constexpr int NCH = ACH + BN/16;
  constexpr int CPW = NCH/4;

  const int lrow = lane >> 2;
  const int lcol = (lane & 3) << 3;

  f32x4 acc[4][BN/32];
  #pragma unroll
  for (int i=0;i<4;i++)
    #pragma unroll
    for (int j=0;j<BN/32;j++)
      acc[i][j] = f32x4{0.f,0.f,0.f,0.f};

  const int nk = (K / SK) >> 5;

  auto stage = [&](int kt, int buf) {
    #pragma unroll
    for (int i = 0; i < CPW; ++i) {
      const int c = w*CPW + i;
      if (c < ACH) {
        const u16* gp = A + (size_t)(row0 + c*16 + lrow) * K + k0 + (kt<<5) + lcol;
        gload16(gp, &sA[buf][c*512]);
      } else {
        const int cb = c - ACH;
        const u16* gp = W + (size_t)(col0 + cb*16 + lrow) * K + k0 + (kt<<5) + lcol;
        gload16(gp, &sB[buf][cb*512]);
      }
    }
  };

  stage(0, 0);
  if (nk > 1) stage(1, 1);

  int cur = 0;
  for (int kt = 0; kt < nk; ++kt) {
    if (kt + 1 < nk) asm volatile("s_waitcnt vmcnt(4)" ::: "memory");
    else             asm volatile("s_waitcnt vmcnt(0)" ::: "memory");
    __builtin_amdgcn_s_barrier();

    if (kt + 2 < nk) stage(kt + 2, (cur + 2 >= 3) ? cur - 1 : cur + 2);

    bf16x8 af[4], bfr[BN/32];
    #pragma unroll
    for (int m=0;m<4;m++)
      af[m] = *(const bf16x8*)&sA[cur][(wr + (m<<4) + r)*32 + (g<<3)];
    #pragma unroll
    for (int n=0;n<BN/32;n++)
      bfr[n] = *(const bf16x8*)&sB[cur][(wc + (n<<4) + r)*32 + (g<<3)];
    #pragma unroll
    for (int m=0;m<4;m++)
      #pragma unroll
      for (int n=0;n<BN/32;n++)
        acc[m][n] = __builtin_amdgcn_mfma_f32_16x16x32_bf16(af[m], bfr[n], acc[m][n], 0, 0, 0);

    cur = (cur + 1 >= 3) ? 0 : cur + 1;
  }

  float* C32 = (float*)Cv + ((SK > 1) ? (size_t)blockIdx.z * M * N : 0);

  #pragma unroll
  for (int n=0;n<BN/32;n++) {
    const int col = col0 + wc + (n<<4) + r;
    const float bv = (SK == 1 || blockIdx.z == 0) ? bias[col] : 0.f;
    #pragma unroll
    for (int m=0;m<4;m++) {
      const int rowb = row0 + wr + (m<<4) + (g<<2);
      #pragma unroll
      for (int q=0;q<4;q++) {
        float v = acc[m][n][q] + bv;
        if (GELU) v = 0.5f * v * (1.f + erff(v * 0.70710678118f));
        if (OUTBF) ((u16*)Cv)[(size_t)(rowb + q) * N + col] = f2bf(v);
        else       C32[(size_t)(rowb + q) * N + col] = v;
      }
    }
  }
}

// ---------------- Flash attention, causal-balanced key-split ----------------
// grid (15 jobs, 32 b*head), jobs of <=3 K-tiles:
//   qt7: 3 parts (3,3,2)  qt6: 3 parts (3,2,2)  qt5/4/3: 2 parts  qt<=2: direct
__global__ __launch_bounds__(256)
void attn_fwd(const u16* __restrict__ qkv, u16* __restrict__ o,
              float* __restrict__ opart, float* __restrict__ mpart,
              float* __restrict__ lpart)
{
  __shared__ __align__(16) u16 sK[128*64];
  __shared__ __align__(16) u16 sV[64*136];
  __shared__ __align__(16) u16 sP[4*32*128];

  const int j  = blockIdx.x;
  int qt, z, ns;
  if      (j < 3)  { qt = 7; z = j;      ns = 3; }
  else if (j < 6)  { qt = 6; z = j - 3;  ns = 3; }
  else if (j < 8)  { qt = 5; z = j - 6;  ns = 2; }
  else if (j < 10) { qt = 4; z = j - 8;  ns = 2; }
  else if (j < 12) { qt = 3; z = j - 10; ns = 2; }
  else             { qt = 14 - j; z = 0; ns = 1; }
  const int T = qt + 1, base = T / ns, rem = T % ns;
  const int kt0 = z * base + (z < rem ? z : rem);
  const int kt1 = kt0 + base + (z < rem ? 1 : 0);

  const int bn = blockIdx.y;
  const int b  = bn >> 4;
  const int hd = bn & 15;

  const int t = threadIdx.x;
  const int lane = t & 63;
  const int w = t >> 6;
  const int r = lane & 15;
  const int g = lane >> 4;

  const float SC = 0.125f * 1.44269504089f;

  bf16x8 qf[2][2];
  #pragma unroll
  for (int m=0;m<2;m++)
    #pragma unroll
    for (int kk=0;kk<2;kk++)
      qf[m][kk] = *(const bf16x8*)(qkv + (size_t)(b*SLEN + qt*128 + w*32 + (m<<4) + r) * QKV3
                                   + hd*HD + (kk<<5) + (g<<3));

  float m_run[2][4], l_run[2][4];
  f32x4 aco[2][4];
  #pragma unroll
  for (int m=0;m<2;m++) {
    #pragma unroll
    for (int q=0;q<4;q++) { m_run[m][q] = -1e30f; l_run[m][q] = 0.f; }
    #pragma unroll
    for (int n=0;n<4;n++) aco[m][n] = f32x4{0.f,0.f,0.f,0.f};
  }

  u16* sPw = sP + (w << 12);

  for (int kt = kt0; kt < kt1; ++kt) {
    __syncthreads();
    {
      const int rl = lane >> 3;
      const int hc = (lane & 7) ^ rl;
      #pragma unroll
      for (int i=0;i<4;i++) {
        const int c = w*4 + i;
        const u16* gp = qkv + (size_t)(b*SLEN + kt*128 + c*8 + rl) * QKV3
                      + E + hd*HD + (hc<<3);
        gload16(gp, &sK[c*512]);
      }
    }
    {
      const int vh = t & 63;
      const int tb = (t >> 6) << 5;
      const u16* vp = qkv + (size_t)(b*SLEN + kt*128 + tb) * QKV3 + 2*E + hd*HD + vh;
      #pragma unroll
      for (int i=0;i<32;i+=2) {
        const u32 v0 = vp[(size_t)i * QKV3];
        const u32 v1 = vp[(size_t)(i+1) * QKV3];
        const int tt = tb + i;
        const int gran = vh*17 + (tt >> 3);
        *(u32*)&sV[(gran<<3) + (tt & 7)] = v0 | (v1 << 16);
      }
    }
    __syncthreads();

    f32x4 s[2][8];
    #pragma unroll
    for (int m=0;m<2;m++)
      #pragma unroll
      for (int n=0;n<8;n++)
        s[m][n] = f32x4{0.f,0.f,0.f,0.f};
    __builtin_amdgcn_s_setprio(1);
    #pragma unroll
    for (int kk=0;kk<2;kk++) {
      bf16x8 kf[8];
      #pragma unroll
      for (int n=0;n<8;n++)
        kf[n] = *(const bf16x8*)&sK[((n<<4)+r)*64 + ((((kk<<2)+g) ^ (r&7))<<3)];
      #pragma unroll
      for (int m=0;m<2;m++)
        #pragma unroll
        for (int n=0;n<8;n++)
          s[m][n] = __builtin_amdgcn_mfma_f32_16x16x32_bf16(qf[m][kk], kf[n], s[m][n], 0,0,0);
    }
    __builtin_amdgcn_s_setprio(0);
    #pragma unroll
    for (int m=0;m<2;m++)
      #pragma unroll
      for (int n=0;n<8;n++)
        #pragma unroll
        for (int q=0;q<4;q++)
          s[m][n][q] *= SC;

    if (kt == qt) {
      #pragma unroll
      for (int m=0;m<2;m++)
        #pragma unroll
        for (int n=0;n<8;n++) {
          const int tg = (n<<4) + r;
          #pragma unroll
          for (int q=0;q<4;q++) {
            const int qg = w*32 + (m<<4) + (g<<2) + q;
            if (tg > qg) s[m][n][q] = -1e30f;
          }
        }
    }

    #pragma unroll
    for (int m=0;m<2;m++) {
      float f[4], rs[4];
      #pragma unroll
      for (int q=0;q<4;q++) {
        float v = s[m][0][q];
        #pragma unroll
        for (int n=1;n<8;n++) v = fmaxf(v, s[m][n][q]);
        v = fmaxf(v, __shfl_xor(v, 1));
        v = fmaxf(v, __shfl_xor(v, 2));
        v = fmaxf(v, __shfl_xor(v, 4));
        v = fmaxf(v, __shfl_xor(v, 8));
        const float mn = fmaxf(m_run[m][q], v);
        f[q] = exp2f(m_run[m][q] - mn);
        m_run[m][q] = mn;
        rs[q] = 0.f;
      }
      #pragma unroll
      for (int n=0;n<8;n++) {
        #pragma unroll
        for (int q=0;q<4;q++) {
          const float p = exp2f(s[m][n][q] - m_run[m][q]);
          rs[q] += p;
          const int prow = (m<<4) + (g<<2) + q;
          const int pch = (n<<1) + (r>>3);
          sPw[(swzP(prow, pch)<<3) + (r&7)] = f2bf(p);
        }
      }
      #pragma unroll
      for (int q=0;q<4;q++) {
        rs[q] += __shfl_xor(rs[q], 1);
        rs[q] += __shfl_xor(rs[q], 2);
        rs[q] += __shfl_xor(rs[q], 4);
        rs[q] += __shfl_xor(rs[q], 8);
        l_run[m][q] = l_run[m][q]*f[q] + rs[q];
      }
      #pragma unroll
      for (int n=0;n<4;n++)
        #pragma unroll
        for (int q=0;q<4;q++)
          aco[m][n][q] *= f[q];
    }

    __builtin_amdgcn_s_waitcnt(0);
    __builtin_amdgcn_sched_barrier(0);

    __builtin_amdgcn_s_setprio(1);
    #pragma unroll
    for (int kk=0;kk<4;kk++) {
      bf16x8 pf[2], vf[4];
      #pragma unroll
      for (int m=0;m<2;m++)
        pf[m] = *(const bf16x8*)&sPw[swzP((m<<4)+r, (kk<<2)+g)<<3];
      #pragma unroll
      for (int n=0;n<4;n++)
        vf[n] = *(const bf16x8*)&sV[(((n<<4)+r)*17 + (kk<<2) + g)<<3];
      #pragma unroll
      for (int m=0;m<2;m++)
        #pragma unroll
        for (int n=0;n<4;n++)
          aco[m][n] = __builtin_amdgcn_mfma_f32_16x16x32_bf16(pf[m], vf[n], aco[m][n], 0,0,0);
    }
    __builtin_amdgcn_s_setprio(0);
  }

  if (ns == 1) {
    #pragma unroll
    for (int m=0;m<2;m++)
      #pragma unroll
      for (int n=0;n<4;n++) {
        const int col = hd*HD + (n<<4) + r;
        #pragma unroll
        for (int q=0;q<4;q++) {
          const int qg = qt*128 + w*32 + (m<<4) + (g<<2) + q;
          o[(size_t)(b*SLEN + qg) * E + col] = f2bf(aco[m][n][q] / l_run[m][q]);
        }
      }
  } else {
    // partial slot: (z, bn, qt-3)
    const size_t pb = (((size_t)z*32 + bn)*5 + (qt - 3)) * 128;
    float* op = opart + pb * 64;
    #pragma unroll
    for (int m=0;m<2;m++)
      #pragma unroll
      for (int n=0;n<4;n++) {
        #pragma unroll
        for (int q=0;q<4;q++) {
          const int row = w*32 + (m<<4) + (g<<2) + q;
          op[(size_t)row * 64 + (n<<4) + r] = aco[m][n][q];
        }
      }
    if (r == 0) {
      #pragma unroll
      for (int m=0;m<2;m++)
        #pragma unroll
        for (int q=0;q<4;q++) {
          const int row = w*32 + (m<<4) + (g<<2) + q;
          mpart[pb + row] = m_run[m][q];
          lpart[pb + row] = l_run[m][q];
        }
    }
  }
}

// ---------------- combine split-attention partials (qt 3..7) ----------------
__global__ __launch_bounds__(256)
void attn_combine(const float* __restrict__ opart, const float* __restrict__ mpart,
                  const float* __restrict__ lpart, u16* __restrict__ o)
{
  const int qi = blockIdx.x;        // 0..4 -> qt 3..7
  const int qt = qi + 3;
  const int np = (qt >= 6) ? 3 : 2;
  const int bn = blockIdx.y;
  const int b  = bn >> 4;
  const int hd = bn & 15;
  const int t = threadIdx.x;
  const int row = t >> 1;
  const int c0  = (t & 1) << 5;

  float4 acc[8];
  #pragma unroll
  for (int i=0;i<8;i++) acc[i] = make_float4(0.f,0.f,0.f,0.f);
  float m = -1e30f, l = 0.f;

  for (int z = 0; z < np; ++z) {
    const size_t pz = (((size_t)z*32 + bn)*5 + qi) * 128 + row;
    const float mz = mpart[pz], lz = lpart[pz];
    const float nm = fmaxf(m, mz);
    const float fo = exp2f(m - nm), fn = exp2f(mz - nm);
    const float4* oz = (const float4*)(opart + pz*64 + c0);
    #pragma unroll
    for (int i=0;i<8;i++) {
      const float4 v = oz[i];
      acc[i].x = acc[i].x*fo + v.x*fn;
      acc[i].y = acc[i].y*fo + v.y*fn;
      acc[i].z = acc[i].z*fo + v.z*fn;
      acc[i].w = acc[i].w*fo + v.w*fn;
    }
    l = l*fo + lz*fn;
    m = nm;
  }
  const float inv = 1.f / l;
  u16* ob = o + (size_t)(b*SLEN + qt*128 + row) * E + hd*HD + c0;
  #pragma unroll
  for (int i=0;i<8;i++) {
    uint2 pk; pk.x = pk2(acc[i].x*inv, acc[i].y*inv); pk.y = pk2(acc[i].z*inv, acc[i].w*inv);
    ((uint2*)ob)[i] = pk;
  }
}

// -------- LayerNorm over (a [+ a2] [+ res]), dual f32/bf16 outputs ----------
__global__ __launch_bounds__(256)
void ln_row(const float* __restrict__ a, const float* __restrict__ a2,
            const float* __restrict__ res,
            const float* __restrict__ lw, const float* __restrict__ lb,
            float* __restrict__ out32, u16* __restrict__ outb)
{
  __shared__ float red[8];
  const int row = blockIdx.x;
  const int i = threadIdx.x;
  float4 v = ((const float4*)(a + ((size_t)row << 10)))[i];
  if (a2 != nullptr) {
    const float4 rv = ((const float4*)(a2 + ((size_t)row << 10)))[i];
    v.x += rv.x; v.y += rv.y; v.z += rv.z; v.w += rv.w;
  }
  if (res != nullptr) {
    const float4 rv = ((const float4*)(res + ((size_t)row << 10)))[i];
    v.x += rv.x; v.y += rv.y; v.z += rv.z; v.w += rv.w;
  }
  float s1 = v.x + v.y + v.z + v.w;
  float s2 = v.x*v.x + v.y*v.y + v.z*v.z + v.w*v.w;
  #pragma unroll
  for (int off=1; off<64; off<<=1) { s1 += __shfl_xor(s1, off); s2 += __shfl_xor(s2, off); }
  if ((i & 63) == 0) { red[(i>>6)*2] = s1; red[(i>>6)*2+1] = s2; }
  __syncthreads();
  s1 = red[0] + red[2] + red[4] + red[6];
  s2 = red[1] + red[3] + red[5] + red[7];
  const float mean = s1 * (1.f/1024.f);
  const float var  = s2 * (1.f/1024.f) - mean*mean;
  const float rstd = rsqrtf(var + 1e-5f);
  const float4 wv = ((const float4*)lw)[i];
  const float4 bv = ((const float4*)lb)[i];
  float4 ov;
  ov.x = (v.x - mean)*rstd*wv.x + bv.x;
  ov.y = (v.y - mean)*rstd*wv.y + bv.y;
  ov.z = (v.z - mean)*rstd*wv.z + bv.z;
  ov.w = (v.w - mean)*rstd*wv.w + bv.w;
  if (out32) ((float4*)(out32 + ((size_t)row << 10)))[i] = ov;
  if (outb) {
    uint2 pk; pk.x = pk2(ov.x, ov.y); pk.y = pk2(ov.z, ov.w);
    ((uint2*)(outb + ((size_t)row << 10)))[i] = pk;
  }
}

// ---------------- Embedding + decoder LN, dual outputs ----------------------
__global__ __launch_bounds__(256)
void embed_ln(const int* __restrict__ x, const float* __restrict__ tok,
              const float* __restrict__ pos, const float* __restrict__ lw,
              const float* __restrict__ lb, float* __restrict__ h32,
              u16* __restrict__ hb)
{
  __shared__ float red[8];
  const int row = blockIdx.x;
  const int s = row & (SLEN-1);
  const int i = threadIdx.x;
  const int id = x[row];
  const float4 tv = ((const float4*)(tok + ((size_t)id << 10)))[i];
  const float4 pv = ((const float4*)(pos + ((size_t)s << 10)))[i];
  float4 v;
  v.x = tv.x + pv.x; v.y = tv.y + pv.y; v.z = tv.z + pv.z; v.w = tv.w + pv.w;
  float s1 = v.x + v.y + v.z + v.w;
  float s2 = v.x*v.x + v.y*v.y + v.z*v.z + v.w*v.w;
  #pragma unroll
  for (int off=1; off<64; off<<=1) { s1 += __shfl_xor(s1, off); s2 += __shfl_xor(s2, off); }
  if ((i & 63) == 0) { red[(i>>6)*2] = s1; red[(i>>6)*2+1] = s2; }
  __syncthreads();
  s1 = red[0] + red[2] + red[4] + red[6];
  s2 = red[1] + red[3] + red[5] + red[7];
  const float mean = s1 * (1.f/1024.f);
  const float var  = s2 * (1.f/1024.f) - mean*mean;
  const float rstd = rsqrtf(var + 1e-5f);
  const float4 wv = ((const float4*)lw)[i];
  const float4 bv = ((const float4*)lb)[i];
  float4 ov;
  ov.x = (v.x - mean)*rstd*wv.x + bv.x;
  ov.y = (v.y - mean)*rstd*wv.y + bv.y;
  ov.z = (v.z - mean)*rstd*wv.z + bv.z;
  ov.w = (v.w - mean)*rstd*wv.w + bv.w;
  ((float4*)(h32 + ((size_t)row << 10)))[i] = ov;
  uint2 pk; pk.x = pk2(ov.x, ov.y); pk.y = pk2(ov.z, ov.w);
  ((uint2*)(hb + ((size_t)row << 10)))[i] = pk;
}

extern "C" void kernel_launch(void* const* d_in, const int* in_sizes, int n_in,
                              void* d_out, int out_size, void* d_ws, size_t ws_size,
                              hipStream_t stream) {
  const int*   x    = (const int*)  d_in[0];
  const float* tok  = (const float*)d_in[1];
  const float* pos  = (const float*)d_in[2];
  const float* decw = (const float*)d_in[3];
  const float* decb = (const float*)d_in[4];
  const float* qkvw = (const float*)d_in[5];
  const float* qkvb = (const float*)d_in[6];
  const float* apw  = (const float*)d_in[7];
  const float* apb  = (const float*)d_in[8];
  const float* l1w  = (const float*)d_in[9];
  const float* l1b  = (const float*)d_in[10];
  const float* fcw  = (const float*)d_in[11];
  const float* fcb  = (const float*)d_in[12];
  const float* mpw  = (const float*)d_in[13];
  const float* mpb  = (const float*)d_in[14];
  const float* l2w  = (const float*)d_in[15];
  const float* l2b  = (const float*)d_in[16];
  const float* finw = (const float*)d_in[17];
  const float* finb = (const float*)d_in[18];
  float* out = (float*)d_out;

  // workspace (~290 MB of ~800 MB)
  char* p = (char*)d_ws;
  float* h32   = (float*)p;                p += (size_t)2048*1024*4;       // 8 MB
  float* part  = (float*)p;                p += (size_t)2*2048*1024*4;     // 16 MB
  float* opart = (float*)p;                p += (size_t)3*32*5*128*64*4;   // 15.7 MB
  float* mpart = (float*)p;                p += (size_t)3*32*5*128*4;      // 240 KB
  float* lpart = (float*)p;                p += (size_t)3*32*5*128*4;      // 240 KB
  u16*   hb    = (u16*)p;                  p += (size_t)2048*1024*2;       // 4 MB
  u16*   qkvB  = (u16*)p;                  p += (size_t)2048*3072*2;       // 12 MB
  u16*   ab    = (u16*)p;                  p += (size_t)2048*1024*2;       // 4 MB
  u16*   fb    = (u16*)p;                  p += (size_t)2048*4096*2;       // 16 MB
  u16*   wq    = (u16*)p;                  p += (size_t)8*3072*1024*2;     // 48 MB
  u16*   wap   = (u16*)p;                  p += (size_t)8*1024*1024*2;     // 16 MB
  u16*   wfc   = (u16*)p;                  p += (size_t)8*4096*1024*2;     // 64 MB
  u16*   wmp   = (u16*)p;                  p += (size_t)8*4096*1024*2;     // 64 MB
  float* part1 = part + (size_t)2048*1024;

  // all-layer weight conversion (nt load, temporal store -> L3-resident)
  f2b<<<2048, 256, 0, stream>>>(qkvw, wq,  8*3072*1024/4);
  f2b<<<1024, 256, 0, stream>>>(apw,  wap, 8*1024*1024/4);
  f2b<<<2048, 256, 0, stream>>>(fcw,  wfc, 8*4096*1024/4);
  f2b<<<2048, 256, 0, stream>>>(mpw,  wmp, 8*4096*1024/4);

  embed_ln<<<2048, 256, 0, stream>>>(x, tok, pos, decw, decb, h32, hb);

  for (int l = 0; l < 8; ++l) {
    const u16* lwq  = wq  + (size_t)l*3072*1024;
    const u16* lwap = wap + (size_t)l*1024*1024;
    const u16* lwfc = wfc + (size_t)l*4096*1024;
    const u16* lwmp = wmp + (size_t)l*4096*1024;

    gemm_lds<128,1,0,1><<<dim3(24,16),   256, 0, stream>>>(hb, lwq,  qkvb + (size_t)l*3072, qkvB, 2048, 3072, 1024);
    attn_fwd<<<dim3(15,32), 256, 0, stream>>>(qkvB, ab, opart, mpart, lpart);
    attn_combine<<<dim3(5,32), 256, 0, stream>>>(opart, mpart, lpart, ab);
    gemm_lds<128,0,0,2><<<dim3(8,16,2),  256, 0, stream>>>(ab, lwap, apb + (size_t)l*1024, part, 2048, 1024, 1024);
    ln_row<<<2048, 256, 0, stream>>>(part, part1, h32, l1w + (size_t)l*1024, l1b + (size_t)l*1024, h32, hb);
    gemm_lds<128,1,1,1><<<dim3(32,16),   256, 0, stream>>>(hb, lwfc, fcb + (size_t)l*4096, fb, 2048, 4096, 1024);
    gemm_lds<128,0,0,2><<<dim3(8,16,2),  256, 0, stream>>>(fb, lwmp, mpb + (size_t)l*1024, part, 2048, 1024, 4096);
    ln_row<<<2048, 256, 0, stream>>>(part, part1, h32, l2w + (size_t)l*1024, l2b + (size_t)l*1024, h32, hb);
  }

  ln_row<<<2048, 256, 0, stream>>>(h32, nullptr, nullptr, finw, finb, out, nullptr);
}

// Round 9
// 1318.019 us; speedup vs baseline: 2.2368x; 1.0729x over previous
//
#include <hip/hip_runtime.h>
#include <hip/hip_bf16.h>

#define E 1024
#define SLEN 1024
#define QKV3 3072
#define HD 64

typedef unsigned short u16;
typedef unsigned int   u32;
typedef __bf16 bf16x8 __attribute__((ext_vector_type(8)));
typedef float  f32x4  __attribute__((ext_vector_type(4)));
typedef float  fv4    __attribute__((ext_vector_type(4)));
typedef u32    uv2    __attribute__((ext_vector_type(2)));

__device__ __forceinline__ u16 f2bf(float f) {
  __hip_bfloat16 h = __float2bfloat16(f);
  return __builtin_bit_cast(u16, h);
}
__device__ __forceinline__ u32 pk2(float a, float b) {
  return (u32)f2bf(a) | ((u32)f2bf(b) << 16);
}
__device__ __forceinline__ float bf2f(u32 lo16) {
  const u32 b = lo16 << 16;
  return __builtin_bit_cast(float, b);
}

// async global->LDS, 16B per lane; LDS dest = wave-uniform base + lane*16
__device__ __forceinline__ void gload16(const u16* g, u16* l) {
  __builtin_amdgcn_global_load_lds(
      (const __attribute__((address_space(1))) void*)g,
      (__attribute__((address_space(3))) void*)l, 16, 0, 0);
}

// P-buffer granule swizzle (attention, verified round 1)
__device__ __forceinline__ int swzP(int row, int ch) { return (row<<4) + (ch ^ (row & 7)); }

// ------------- f32 -> bf16 streaming convert ---------------------------------
__global__ __launch_bounds__(256)
void f2b(const float* __restrict__ src, u16* __restrict__ dst, int n4)
{
  const int stride = gridDim.x * 256;
  const fv4* s4 = (const fv4*)src;
  uv2* d2 = (uv2*)dst;
  for (int i = blockIdx.x * 256 + threadIdx.x; i < n4; i += stride) {
    const fv4 v = __builtin_nontemporal_load(s4 + i);
    uv2 o; o.x = pk2(v.x, v.y); o.y = pk2(v.z, v.w);
    d2[i] = o;
  }
}

// ---------------- GEMM: C = A[M][K] @ W[N][K]^T + bias ----------------------
// bf16 A,W via global_load_lds; BM=128, BK=32, 256 threads (2x2 waves).
// 3-buffer ring, depth-2 prefetch, counted vmcnt, raw s_barrier.
// SK>1: split-K bf16 partial planes (bias on plane 0).
// SWCX/SWCY: 2D-chunked XCD swizzle (requires gx%CX==0, gy%CY==0,
//            (gx/CX)*(gy/CY)*SK == 8, grid size % 8 == 0).
template<int BN, int OUTBF, int GELU, int SK, int SWCX, int SWCY>
__global__ __launch_bounds__(256)
void gemm_lds(const u16* __restrict__ A, const u16* __restrict__ W,
              const float* __restrict__ bias, void* __restrict__ Cv,
              int M, int N, int K)
{
  static_assert(!(GELU && SK > 1), "gelu needs full sum");
  constexpr int BM = 128;
  __shared__ __align__(16) u16 sA[3][BM*32];
  __shared__ __align__(16) u16 sB[3][BN*32];

  int bx, by, bz;
  if (SWCX > 0) {
    const int gx = gridDim.x, gy = gridDim.y;
    const int bid = blockIdx.x + gx*(blockIdx.y + gy*blockIdx.z);
    const int nchx = gx / SWCX;
    const int nchy = gy / SWCY;
    const int xcd = bid & 7;
    const int within = bid >> 3;
    const int cz  = xcd / (nchx*nchy);
    const int rem = xcd % (nchx*nchy);
    bx = (rem % nchx)*SWCX + within % SWCX;
    by = (rem / nchx)*SWCY + within / SWCX;
    bz = cz;
  } else {
    bx = blockIdx.x; by = blockIdx.y; bz = blockIdx.z;
  }

  const int t = threadIdx.x;
  const int lane = t & 63;
  const int w = t >> 6;
  const int r = lane & 15;
  const int g = lane >> 4;
  const int wr = (w >> 1) * 64;
  const int wc = (w & 1) * (BN/2);

  const int row0 = by * BM;
  const int col0 = bx * BN;
  const int k0   = (SK > 1) ? bz * (K / SK) : 0;

  constexpr int ACH = BM/16;
  constexpr int NCH = ACH + BN/16;
  constexpr int CPW = NCH/4;

  const int lrow = lane >> 2;
  const int lcol = (lane & 3) << 3;

  f32x4 acc[4][BN/32];
  #pragma unroll
  for (int i=0;i<4;i++)
    #pragma unroll
    for (int j=0;j<BN/32;j++)
      acc[i][j] = f32x4{0.f,0.f,0.f,0.f};

  const int nk = (K / SK) >> 5;

  auto stage = [&](int kt, int buf) {
    #pragma unroll
    for (int i = 0; i < CPW; ++i) {
      const int c = w*CPW + i;
      if (c < ACH) {
        const u16* gp = A + (size_t)(row0 + c*16 + lrow) * K + k0 + (kt<<5) + lcol;
        gload16(gp, &sA[buf][c*512]);
      } else {
        const int cb = c - ACH;
        const u16* gp = W + (size_t)(col0 + cb*16 + lrow) * K + k0 + (kt<<5) + lcol;
        gload16(gp, &sB[buf][cb*512]);
      }
    }
  };

  stage(0, 0);
  if (nk > 1) stage(1, 1);

  int cur = 0;
  for (int kt = 0; kt < nk; ++kt) {
    if (kt + 1 < nk) asm volatile("s_waitcnt vmcnt(4)" ::: "memory");
    else             asm volatile("s_waitcnt vmcnt(0)" ::: "memory");
    __builtin_amdgcn_s_barrier();

    if (kt + 2 < nk) stage(kt + 2, (cur + 2 >= 3) ? cur - 1 : cur + 2);

    bf16x8 af[4], bfr[BN/32];
    #pragma unroll
    for (int m=0;m<4;m++)
      af[m] = *(const bf16x8*)&sA[cur][(wr + (m<<4) + r)*32 + (g<<3)];
    #pragma unroll
    for (int n=0;n<BN/32;n++)
      bfr[n] = *(const bf16x8*)&sB[cur][(wc + (n<<4) + r)*32 + (g<<3)];
    #pragma unroll
    for (int m=0;m<4;m++)
      #pragma unroll
      for (int n=0;n<BN/32;n++)
        acc[m][n] = __builtin_amdgcn_mfma_f32_16x16x32_bf16(af[m], bfr[n], acc[m][n], 0, 0, 0);

    cur = (cur + 1 >= 3) ? 0 : cur + 1;
  }

  u16*   Cb  = (u16*)Cv   + ((SK > 1) ? (size_t)bz * M * N : 0);
  float* C32 = (float*)Cv;

  #pragma unroll
  for (int n=0;n<BN/32;n++) {
    const int col = col0 + wc + (n<<4) + r;
    const float bv = (SK == 1 || bz == 0) ? bias[col] : 0.f;
    #pragma unroll
    for (int m=0;m<4;m++) {
      const int rowb = row0 + wr + (m<<4) + (g<<2);
      #pragma unroll
      for (int q=0;q<4;q++) {
        float v = acc[m][n][q] + bv;
        if (GELU) v = 0.5f * v * (1.f + erff(v * 0.70710678118f));
        if (OUTBF) Cb[(size_t)(rowb + q) * N + col] = f2bf(v);
        else       C32[(size_t)(rowb + q) * N + col] = v;
      }
    }
  }
}

// ---------------- Flash attention, causal-balanced key-split ----------------
__global__ __launch_bounds__(256)
void attn_fwd(const u16* __restrict__ qkv, u16* __restrict__ o,
              float* __restrict__ opart, float* __restrict__ mpart,
              float* __restrict__ lpart)
{
  __shared__ __align__(16) u16 sK[128*64];
  __shared__ __align__(16) u16 sV[64*136];
  __shared__ __align__(16) u16 sP[4*32*128];

  const int j  = blockIdx.x;
  int qt, z, ns;
  if      (j < 3)  { qt = 7; z = j;      ns = 3; }
  else if (j < 6)  { qt = 6; z = j - 3;  ns = 3; }
  else if (j < 8)  { qt = 5; z = j - 6;  ns = 2; }
  else if (j < 10) { qt = 4; z = j - 8;  ns = 2; }
  else if (j < 12) { qt = 3; z = j - 10; ns = 2; }
  else             { qt = 14 - j; z = 0; ns = 1; }
  const int T = qt + 1, base = T / ns, rem = T % ns;
  const int kt0 = z * base + (z < rem ? z : rem);
  const int kt1 = kt0 + base + (z < rem ? 1 : 0);

  const int bn = blockIdx.y;
  const int b  = bn >> 4;
  const int hd = bn & 15;

  const int t = threadIdx.x;
  const int lane = t & 63;
  const int w = t >> 6;
  const int r = lane & 15;
  const int g = lane >> 4;

  const float SC = 0.125f * 1.44269504089f;

  bf16x8 qf[2][2];
  #pragma unroll
  for (int m=0;m<2;m++)
    #pragma unroll
    for (int kk=0;kk<2;kk++)
      qf[m][kk] = *(const bf16x8*)(qkv + (size_t)(b*SLEN + qt*128 + w*32 + (m<<4) + r) * QKV3
                                   + hd*HD + (kk<<5) + (g<<3));

  float m_run[2][4], l_run[2][4];
  f32x4 aco[2][4];
  #pragma unroll
  for (int m=0;m<2;m++) {
    #pragma unroll
    for (int q=0;q<4;q++) { m_run[m][q] = -1e30f; l_run[m][q] = 0.f; }
    #pragma unroll
    for (int n=0;n<4;n++) aco[m][n] = f32x4{0.f,0.f,0.f,0.f};
  }

  u16* sPw = sP + (w << 12);

  for (int kt = kt0; kt < kt1; ++kt) {
    __syncthreads();
    {
      const int rl = lane >> 3;
      const int hc = (lane & 7) ^ rl;
      #pragma unroll
      for (int i=0;i<4;i++) {
        const int c = w*4 + i;
        const u16* gp = qkv + (size_t)(b*SLEN + kt*128 + c*8 + rl) * QKV3
                      + E + hd*HD + (hc<<3);
        gload16(gp, &sK[c*512]);
      }
    }
    {
      const int vh = t & 63;
      const int tb = (t >> 6) << 5;
      const u16* vp = qkv + (size_t)(b*SLEN + kt*128 + tb) * QKV3 + 2*E + hd*HD + vh;
      #pragma unroll
      for (int i=0;i<32;i+=2) {
        const u32 v0 = vp[(size_t)i * QKV3];
        const u32 v1 = vp[(size_t)(i+1) * QKV3];
        const int tt = tb + i;
        const int gran = vh*17 + (tt >> 3);
        *(u32*)&sV[(gran<<3) + (tt & 7)] = v0 | (v1 << 16);
      }
    }
    __syncthreads();

    f32x4 s[2][8];
    #pragma unroll
    for (int m=0;m<2;m++)
      #pragma unroll
      for (int n=0;n<8;n++)
        s[m][n] = f32x4{0.f,0.f,0.f,0.f};
    __builtin_amdgcn_s_setprio(1);
    #pragma unroll
    for (int kk=0;kk<2;kk++) {
      bf16x8 kf[8];
      #pragma unroll
      for (int n=0;n<8;n++)
        kf[n] = *(const bf16x8*)&sK[((n<<4)+r)*64 + ((((kk<<2)+g) ^ (r&7))<<3)];
      #pragma unroll
      for (int m=0;m<2;m++)
        #pragma unroll
        for (int n=0;n<8;n++)
          s[m][n] = __builtin_amdgcn_mfma_f32_16x16x32_bf16(qf[m][kk], kf[n], s[m][n], 0,0,0);
    }
    __builtin_amdgcn_s_setprio(0);
    #pragma unroll
    for (int m=0;m<2;m++)
      #pragma unroll
      for (int n=0;n<8;n++)
        #pragma unroll
        for (int q=0;q<4;q++)
          s[m][n][q] *= SC;

    if (kt == qt) {
      #pragma unroll
      for (int m=0;m<2;m++)
        #pragma unroll
        for (int n=0;n<8;n++) {
          const int tg = (n<<4) + r;
          #pragma unroll
          for (int q=0;q<4;q++) {
            const int qg = w*32 + (m<<4) + (g<<2) + q;
            if (tg > qg) s[m][n][q] = -1e30f;
          }
        }
    }

    #pragma unroll
    for (int m=0;m<2;m++) {
      float f[4], rs[4];
      #pragma unroll
      for (int q=0;q<4;q++) {
        float v = s[m][0][q];
        #pragma unroll
        for (int n=1;n<8;n++) v = fmaxf(v, s[m][n][q]);
        v = fmaxf(v, __shfl_xor(v, 1));
        v = fmaxf(v, __shfl_xor(v, 2));
        v = fmaxf(v, __shfl_xor(v, 4));
        v = fmaxf(v, __shfl_xor(v, 8));
        const float mn = fmaxf(m_run[m][q], v);
        f[q] = exp2f(m_run[m][q] - mn);
        m_run[m][q] = mn;
        rs[q] = 0.f;
      }
      #pragma unroll
      for (int n=0;n<8;n++) {
        #pragma unroll
        for (int q=0;q<4;q++) {
          const float p = exp2f(s[m][n][q] - m_run[m][q]);
          rs[q] += p;
          const int prow = (m<<4) + (g<<2) + q;
          const int pch = (n<<1) + (r>>3);
          sPw[(swzP(prow, pch)<<3) + (r&7)] = f2bf(p);
        }
      }
      #pragma unroll
      for (int q=0;q<4;q++) {
        rs[q] += __shfl_xor(rs[q], 1);
        rs[q] += __shfl_xor(rs[q], 2);
        rs[q] += __shfl_xor(rs[q], 4);
        rs[q] += __shfl_xor(rs[q], 8);
        l_run[m][q] = l_run[m][q]*f[q] + rs[q];
      }
      #pragma unroll
      for (int n=0;n<4;n++)
        #pragma unroll
        for (int q=0;q<4;q++)
          aco[m][n][q] *= f[q];
    }

    __builtin_amdgcn_s_waitcnt(0);
    __builtin_amdgcn_sched_barrier(0);

    __builtin_amdgcn_s_setprio(1);
    #pragma unroll
    for (int kk=0;kk<4;kk++) {
      bf16x8 pf[2], vf[4];
      #pragma unroll
      for (int m=0;m<2;m++)
        pf[m] = *(const bf16x8*)&sPw[swzP((m<<4)+r, (kk<<2)+g)<<3];
      #pragma unroll
      for (int n=0;n<4;n++)
        vf[n] = *(const bf16x8*)&sV[(((n<<4)+r)*17 + (kk<<2) + g)<<3];
      #pragma unroll
      for (int m=0;m<2;m++)
        #pragma unroll
        for (int n=0;n<4;n++)
          aco[m][n] = __builtin_amdgcn_mfma_f32_16x16x32_bf16(pf[m], vf[n], aco[m][n], 0,0,0);
    }
    __builtin_amdgcn_s_setprio(0);
  }

  if (ns == 1) {
    #pragma unroll
    for (int m=0;m<2;m++)
      #pragma unroll
      for (int n=0;n<4;n++) {
        const int col = hd*HD + (n<<4) + r;
        #pragma unroll
        for (int q=0;q<4;q++) {
          const int qg = qt*128 + w*32 + (m<<4) + (g<<2) + q;
          o[(size_t)(b*SLEN + qg) * E + col] = f2bf(aco[m][n][q] / l_run[m][q]);
        }
      }
  } else {
    const size_t pb = (((size_t)z*32 + bn)*5 + (qt - 3)) * 128;
    float* op = opart + pb * 64;
    #pragma unroll
    for (int m=0;m<2;m++)
      #pragma unroll
      for (int n=0;n<4;n++) {
        #pragma unroll
        for (int q=0;q<4;q++) {
          const int row = w*32 + (m<<4) + (g<<2) + q;
          op[(size_t)row * 64 + (n<<4) + r] = aco[m][n][q];
        }
      }
    if (r == 0) {
      #pragma unroll
      for (int m=0;m<2;m++)
        #pragma unroll
        for (int q=0;q<4;q++) {
          const int row = w*32 + (m<<4) + (g<<2) + q;
          mpart[pb + row] = m_run[m][q];
          lpart[pb + row] = l_run[m][q];
        }
    }
  }
}

// ---------------- combine split-attention partials (qt 3..7) ----------------
__global__ __launch_bounds__(256)
void attn_combine(const float* __restrict__ opart, const float* __restrict__ mpart,
                  const float* __restrict__ lpart, u16* __restrict__ o)
{
  const int qi = blockIdx.x;        // 0..4 -> qt 3..7
  const int qt = qi + 3;
  const int np = (qt >= 6) ? 3 : 2;
  const int bn = blockIdx.y;
  const int b  = bn >> 4;
  const int hd = bn & 15;
  const int t = threadIdx.x;
  const int row = t >> 1;
  const int c0  = (t & 1) << 5;

  float4 acc[8];
  #pragma unroll
  for (int i=0;i<8;i++) acc[i] = make_float4(0.f,0.f,0.f,0.f);
  float m = -1e30f, l = 0.f;

  for (int z = 0; z < np; ++z) {
    const size_t pz = (((size_t)z*32 + bn)*5 + qi) * 128 + row;
    const float mz = mpart[pz], lz = lpart[pz];
    const float nm = fmaxf(m, mz);
    const float fo = exp2f(m - nm), fn = exp2f(mz - nm);
    const float4* oz = (const float4*)(opart + pz*64 + c0);
    #pragma unroll
    for (int i=0;i<8;i++) {
      const float4 v = oz[i];
      acc[i].x = acc[i].x*fo + v.x*fn;
      acc[i].y = acc[i].y*fo + v.y*fn;
      acc[i].z = acc[i].z*fo + v.z*fn;
      acc[i].w = acc[i].w*fo + v.w*fn;
    }
    l = l*fo + lz*fn;
    m = nm;
  }
  const float inv = 1.f / l;
  u16* ob = o + (size_t)(b*SLEN + qt*128 + row) * E + hd*HD + c0;
  #pragma unroll
  for (int i=0;i<8;i++) {
    uint2 pk; pk.x = pk2(acc[i].x*inv, acc[i].y*inv); pk.y = pk2(acc[i].z*inv, acc[i].w*inv);
    ((uint2*)ob)[i] = pk;
  }
}

// -------- LayerNorm over bf16 inputs (a0 [+ a1] [+ res]) --------------------
// outputs: bf16 (outb) and/or f32 (out32)
__global__ __launch_bounds__(256)
void ln_bf(const u16* __restrict__ a0, const u16* __restrict__ a1,
           const u16* __restrict__ res,
           const float* __restrict__ lw, const float* __restrict__ lb,
           u16* __restrict__ outb, float* __restrict__ out32)
{
  __shared__ float red[8];
  const int row = blockIdx.x;
  const int i = threadIdx.x;
  const size_t base = (size_t)row << 10;

  uint2 pk0 = ((const uint2*)(a0 + base))[i];
  float4 v;
  v.x = bf2f(pk0.x & 0xffff); v.y = bf2f(pk0.x >> 16);
  v.z = bf2f(pk0.y & 0xffff); v.w = bf2f(pk0.y >> 16);
  if (a1 != nullptr) {
    uint2 pk1 = ((const uint2*)(a1 + base))[i];
    v.x += bf2f(pk1.x & 0xffff); v.y += bf2f(pk1.x >> 16);
    v.z += bf2f(pk1.y & 0xffff); v.w += bf2f(pk1.y >> 16);
  }
  if (res != nullptr) {
    uint2 pk1 = ((const uint2*)(res + base))[i];
    v.x += bf2f(pk1.x & 0xffff); v.y += bf2f(pk1.x >> 16);
    v.z += bf2f(pk1.y & 0xffff); v.w += bf2f(pk1.y >> 16);
  }

  float s1 = v.x + v.y + v.z + v.w;
  float s2 = v.x*v.x + v.y*v.y + v.z*v.z + v.w*v.w;
  #pragma unroll
  for (int off=1; off<64; off<<=1) { s1 += __shfl_xor(s1, off); s2 += __shfl_xor(s2, off); }
  if ((i & 63) == 0) { red[(i>>6)*2] = s1; red[(i>>6)*2+1] = s2; }
  __syncthreads();
  s1 = red[0] + red[2] + red[4] + red[6];
  s2 = red[1] + red[3] + red[5] + red[7];
  const float mean = s1 * (1.f/1024.f);
  const float var  = s2 * (1.f/1024.f) - mean*mean;
  const float rstd = rsqrtf(var + 1e-5f);
  const float4 wv = ((const float4*)lw)[i];
  const float4 bv = ((const float4*)lb)[i];
  float4 ov;
  ov.x = (v.x - mean)*rstd*wv.x + bv.x;
  ov.y = (v.y - mean)*rstd*wv.y + bv.y;
  ov.z = (v.z - mean)*rstd*wv.z + bv.z;
  ov.w = (v.w - mean)*rstd*wv.w + bv.w;
  if (outb) {
    uint2 pk; pk.x = pk2(ov.x, ov.y); pk.y = pk2(ov.z, ov.w);
    ((uint2*)(outb + base))[i] = pk;
  }
  if (out32) ((float4*)(out32 + base))[i] = ov;
}

// ---------------- Embedding + decoder LN (bf16 out) -------------------------
__global__ __launch_bounds__(256)
void embed_ln(const int* __restrict__ x, const float* __restrict__ tok,
              const float* __restrict__ pos, const float* __restrict__ lw,
              const float* __restrict__ lb, u16* __restrict__ hb)
{
  __shared__ float red[8];
  const int row = blockIdx.x;
  const int s = row & (SLEN-1);
  const int i = threadIdx.x;
  const int id = x[row];
  const float4 tv = ((const float4*)(tok + ((size_t)id << 10)))[i];
  const float4 pv = ((const float4*)(pos + ((size_t)s << 10)))[i];
  float4 v;
  v.x = tv.x + pv.x; v.y = tv.y + pv.y; v.z = tv.z + pv.z; v.w = tv.w + pv.w;
  float s1 = v.x + v.y + v.z + v.w;
  float s2 = v.x*v.x + v.y*v.y + v.z*v.z + v.w*v.w;
  #pragma unroll
  for (int off=1; off<64; off<<=1) { s1 += __shfl_xor(s1, off); s2 += __shfl_xor(s2, off); }
  if ((i & 63) == 0) { red[(i>>6)*2] = s1; red[(i>>6)*2+1] = s2; }
  __syncthreads();
  s1 = red[0] + red[2] + red[4] + red[6];
  s2 = red[1] + red[3] + red[5] + red[7];
  const float mean = s1 * (1.f/1024.f);
  const float var  = s2 * (1.f/1024.f) - mean*mean;
  const float rstd = rsqrtf(var + 1e-5f);
  const float4 wv = ((const float4*)lw)[i];
  const float4 bv = ((const float4*)lb)[i];
  float4 ov;
  ov.x = (v.x - mean)*rstd*wv.x + bv.x;
  ov.y = (v.y - mean)*rstd*wv.y + bv.y;
  ov.z = (v.z - mean)*rstd*wv.z + bv.z;
  ov.w = (v.w - mean)*rstd*wv.w + bv.w;
  uint2 pk; pk.x = pk2(ov.x, ov.y); pk.y = pk2(ov.z, ov.w);
  ((uint2*)(hb + ((size_t)row << 10)))[i] = pk;
}

extern "C" void kernel_launch(void* const* d_in, const int* in_sizes, int n_in,
                              void* d_out, int out_size, void* d_ws, size_t ws_size,
                              hipStream_t stream) {
  const int*   x    = (const int*)  d_in[0];
  const float* tok  = (const float*)d_in[1];
  const float* pos  = (const float*)d_in[2];
  const float* decw = (const float*)d_in[3];
  const float* decb = (const float*)d_in[4];
  const float* qkvw = (const float*)d_in[5];
  const float* qkvb = (const float*)d_in[6];
  const float* apw  = (const float*)d_in[7];
  const float* apb  = (const float*)d_in[8];
  const float* l1w  = (const float*)d_in[9];
  const float* l1b  = (const float*)d_in[10];
  const float* fcw  = (const float*)d_in[11];
  const float* fcb  = (const float*)d_in[12];
  const float* mpw  = (const float*)d_in[13];
  const float* mpb  = (const float*)d_in[14];
  const float* l2w  = (const float*)d_in[15];
  const float* l2b  = (const float*)d_in[16];
  const float* finw = (const float*)d_in[17];
  const float* finb = (const float*)d_in[18];
  float* out = (float*)d_out;

  // workspace (~270 MB of ~800 MB)
  char* p = (char*)d_ws;
  float* opart = (float*)p;                p += (size_t)3*32*5*128*64*4;   // 15.7 MB
  float* mpart = (float*)p;                p += (size_t)3*32*5*128*4;      // 240 KB
  float* lpart = (float*)p;                p += (size_t)3*32*5*128*4;      // 240 KB
  u16*   partb = (u16*)p;                  p += (size_t)2*2048*1024*2;     // 8 MB (2 bf16 planes)
  u16*   hb    = (u16*)p;                  p += (size_t)2048*1024*2;       // 4 MB
  u16*   qkvB  = (u16*)p;                  p += (size_t)2048*3072*2;       // 12 MB
  u16*   ab    = (u16*)p;                  p += (size_t)2048*1024*2;       // 4 MB
  u16*   fb    = (u16*)p;                  p += (size_t)2048*4096*2;       // 16 MB
  u16*   wq    = (u16*)p;                  p += (size_t)8*3072*1024*2;     // 48 MB
  u16*   wap   = (u16*)p;                  p += (size_t)8*1024*1024*2;     // 16 MB
  u16*   wfc   = (u16*)p;                  p += (size_t)8*4096*1024*2;     // 64 MB
  u16*   wmp   = (u16*)p;                  p += (size_t)8*4096*1024*2;     // 64 MB
  u16*   partb1 = partb + (size_t)2048*1024;

  // all-layer weight conversion (nt load, temporal store -> L3-resident)
  f2b<<<2048, 256, 0, stream>>>(qkvw, wq,  8*3072*1024/4);
  f2b<<<1024, 256, 0, stream>>>(apw,  wap, 8*1024*1024/4);
  f2b<<<2048, 256, 0, stream>>>(fcw,  wfc, 8*4096*1024/4);
  f2b<<<2048, 256, 0, stream>>>(mpw,  wmp, 8*4096*1024/4);

  embed_ln<<<2048, 256, 0, stream>>>(x, tok, pos, decw, decb, hb);

  for (int l = 0; l < 8; ++l) {
    const u16* lwq  = wq  + (size_t)l*3072*1024;
    const u16* lwap = wap + (size_t)l*1024*1024;
    const u16* lwfc = wfc + (size_t)l*4096*1024;
    const u16* lwmp = wmp + (size_t)l*4096*1024;

    // qkv: grid 24x16=384, chunks 6x8 -> (24/6)*(16/8)=8 XCD chunks
    gemm_lds<128,1,0,1,6,8><<<dim3(24,16),  256, 0, stream>>>(hb, lwq,  qkvb + (size_t)l*3072, qkvB, 2048, 3072, 1024);
    attn_fwd<<<dim3(15,32), 256, 0, stream>>>(qkvB, ab, opart, mpart, lpart);
    attn_combine<<<dim3(5,32), 256, 0, stream>>>(opart, mpart, lpart, ab);
    // attn-proj split-K=2: grid 8x16x2=256, chunks 4x8 per z -> 2*2*2=8
    gemm_lds<128,1,0,2,4,8><<<dim3(8,16,2), 256, 0, stream>>>(ab, lwap, apb + (size_t)l*1024, partb, 2048, 1024, 1024);
    ln_bf<<<2048, 256, 0, stream>>>(partb, partb1, hb, l1w + (size_t)l*1024, l1b + (size_t)l*1024, hb, nullptr);
    // fc: grid 32x16=512, chunks 8x8 -> 4*2=8
    gemm_lds<128,1,1,1,8,8><<<dim3(32,16),  256, 0, stream>>>(hb, lwfc, fcb + (size_t)l*4096, fb, 2048, 4096, 1024);
    // mlp-proj split-K=2
    gemm_lds<128,1,0,2,4,8><<<dim3(8,16,2), 256, 0, stream>>>(fb, lwmp, mpb + (size_t)l*1024, partb, 2048, 1024, 4096);
    ln_bf<<<2048, 256, 0, stream>>>(partb, partb1, hb, l2w + (size_t)l*1024, l2b + (size_t)l*1024, hb, nullptr);
  }

  ln_bf<<<2048, 256, 0, stream>>>(hb, nullptr, nullptr, finw, finb, nullptr, out);
}